// Round 2
// baseline (407.540 us; speedup 1.0000x reference)
//
#include <hip/hip_runtime.h>
#include <cstdint>
#include <cstddef>

// Problem constants (MultiHeadAttention: B=4, T=2048, d_model=1024, H=16, hd=64)
#define D_MODEL 1024
#define SEQQ    2048
#define NBATCH  4
#define NHEAD   16
#define HDIM    64
#define MTOT    (NBATCH * SEQQ)   // 8192 rows

typedef __attribute__((ext_vector_type(8))) short short8;   // 8 x bf16 (4 VGPRs) — MFMA A/B frag
typedef __attribute__((ext_vector_type(4))) float floatx4;  // MFMA C/D frag
typedef unsigned short u16;                                  // bf16 bits

__device__ __forceinline__ u16 f2bf(float f) {
  union { float f; uint32_t u; } a; a.f = f;
  uint32_t u = a.u;
  u += 0x7fffu + ((u >> 16) & 1u);   // RN-even
  return (u16)(u >> 16);
}

__device__ __forceinline__ floatx4 mfma16(short8 a, short8 b, floatx4 c) {
  return __builtin_amdgcn_mfma_f32_16x16x32_bf16(a, b, c, 0, 0, 0);
}

// async global->LDS, 16B per lane. LDS dest = wave-uniform base + lane*16.
__device__ __forceinline__ void load_lds16(const void* g, void* l) {
  __builtin_amdgcn_global_load_lds(
      (const __attribute__((address_space(1))) uint32_t*)g,
      (__attribute__((address_space(3))) uint32_t*)l, 16, 0, 0);
}

// ---------------------------------------------------------------- fused casts f32->bf16
// blocks [0, 8192): X. blocks [8192, 12288): weights, 1024 blocks each.
__global__ __launch_bounds__(256) void k_cast_all(
    const float* __restrict__ X, const float* __restrict__ w0,
    const float* __restrict__ w1, const float* __restrict__ w2,
    const float* __restrict__ w3,
    u16* __restrict__ xb, u16* __restrict__ y0, u16* __restrict__ y1,
    u16* __restrict__ y2, u16* __restrict__ y3) {
  const int bx = blockIdx.x;
  const float* src; u16* dst; int i;
  if (bx < 8192) {
    src = X; dst = xb; i = (bx * 256 + threadIdx.x) * 4;
  } else {
    const int w = (bx - 8192) >> 10;
    src = (w == 0) ? w0 : (w == 1) ? w1 : (w == 2) ? w2 : w3;
    dst = (w == 0) ? y0 : (w == 1) ? y1 : (w == 2) ? y2 : y3;
    i = (((bx - 8192) & 1023) * 256 + threadIdx.x) * 4;
  }
  float4 v = *(const float4*)(src + i);
  ushort4 o;
  o.x = f2bf(v.x); o.y = f2bf(v.y); o.z = f2bf(v.z); o.w = f2bf(v.w);
  *(ushort4*)(dst + i) = o;
}

// ---------------------------------------------------------------- GEMM  C = A @ B^T (+bias)
// ascaleQ: extra scale on the z==0 output (folds 1/sqrt(hd)*log2e into Q).
// z==2 (V projection): epilogue writes TRANSPOSED into Vt [bh][64][2048].
__global__ __launch_bounds__(256) void k_gemm_bt(
    const u16* __restrict__ A,
    const u16* __restrict__ B0, const u16* __restrict__ B1, const u16* __restrict__ B2,
    void* __restrict__ C0, void* __restrict__ C1, u16* __restrict__ VtOut,
    const float* __restrict__ bias, int M, int N, int K, int f32out, float ascaleQ) {
  __shared__ __align__(16) u16 As[128 * 64];
  __shared__ __align__(16) u16 Bs[128 * 64];
  const int tid = threadIdx.x;
  const int lane = tid & 63, wave = tid >> 6;
  const int quad = lane >> 4, l15 = lane & 15;
  const int m0 = blockIdx.y * 128, n0 = blockIdx.x * 128;
  const int wr = wave >> 1, wc = wave & 1;
  const u16* Bm = (blockIdx.z == 0) ? B0 : (blockIdx.z == 1 ? B1 : B2);
  void* Cm = (blockIdx.z == 0) ? C0 : C1;
  const float ascale = (blockIdx.z == 0) ? ascaleQ : 1.0f;

  floatx4 acc[4][4];
#pragma unroll
  for (int i = 0; i < 4; ++i)
#pragma unroll
    for (int j = 0; j < 4; ++j) acc[i][j] = (floatx4){0.f, 0.f, 0.f, 0.f};

  const int srow = tid >> 3;                       // 0..31
  const int scolx = ((tid & 7) * 8) ^ ((srow & 7) * 8);  // swizzled source column
  const u16* Ag = A + (size_t)(m0 + srow) * K + scolx;
  const u16* Bg = Bm + (size_t)(n0 + srow) * K + scolx;

  for (int kt = 0; kt < K; kt += 64) {
    __syncthreads();
#pragma unroll
    for (int p = 0; p < 4; ++p) {
      load_lds16(Ag + (size_t)(p * 32) * K + kt, &As[p * 2048 + wave * 512]);
      load_lds16(Bg + (size_t)(p * 32) * K + kt, &Bs[p * 2048 + wave * 512]);
    }
    __syncthreads();

    short8 af[2][4], bfg[2][4];
#pragma unroll
    for (int ks = 0; ks < 2; ++ks) {
      const int kkx = (ks * 32 + quad * 8) ^ ((l15 & 7) * 8);
#pragma unroll
      for (int i = 0; i < 4; ++i) {
        af[ks][i]  = *(const short8*)&As[(wr * 64 + i * 16 + l15) * 64 + kkx];
        bfg[ks][i] = *(const short8*)&Bs[(wc * 64 + i * 16 + l15) * 64 + kkx];
      }
    }
#pragma unroll
    for (int ks = 0; ks < 2; ++ks)
#pragma unroll
      for (int mi = 0; mi < 4; ++mi)
#pragma unroll
        for (int ni = 0; ni < 4; ++ni)
          acc[mi][ni] = mfma16(af[ks][mi], bfg[ks][ni], acc[mi][ni]);
  }

  // Epilogue. C/D layout: col = lane&15, row = quad*4 + reg (m89-verified).
  if (blockIdx.z == 2) {
    // transposed V write: Vt[(b*16+h)*64 + d][t], 4 regs = t..t+3 contiguous
#pragma unroll
    for (int mi = 0; mi < 4; ++mi) {
#pragma unroll
      for (int ni = 0; ni < 4; ++ni) {
        const int row = m0 + wr * 64 + mi * 16 + quad * 4;   // token
        const int col = n0 + wc * 64 + ni * 16 + l15;        // channel
        const int b = row >> 11, t = row & 2047;
        const int h = col >> 6, d = col & 63;
        ushort4 pk;
        pk.x = f2bf(acc[mi][ni][0]); pk.y = f2bf(acc[mi][ni][1]);
        pk.z = f2bf(acc[mi][ni][2]); pk.w = f2bf(acc[mi][ni][3]);
        *(ushort4*)(VtOut + (((size_t)(b * 16 + h) * 64 + d) * SEQQ + t)) = pk;
      }
    }
    return;
  }
#pragma unroll
  for (int mi = 0; mi < 4; ++mi) {
#pragma unroll
    for (int ni = 0; ni < 4; ++ni) {
      const int row = m0 + wr * 64 + mi * 16 + quad * 4;
      const int col = n0 + wc * 64 + ni * 16 + l15;
      const float bv = bias ? bias[col] : 0.f;
#pragma unroll
      for (int r = 0; r < 4; ++r) {
        const float v = acc[mi][ni][r] * ascale + bv;
        if (f32out) ((float*)Cm)[(size_t)(row + r) * N + col] = v;
        else        ((u16*)Cm)[(size_t)(row + r) * N + col] = f2bf(v);
      }
    }
  }
}

// ---------------------------------------------------------------- flash attention
// r4/r6 structure (paired q-tiles (p,31-p), 64-row granularity, 4 waves x 16 q),
// double-buffered K/V staging, ONE barrier per iteration.
// P redistribution (S^T -> PV A-operand) fully in registers via
// v_permlane32_swap_b32 + v_permlane16_swap_b32. Exchange is confined to the
// 4-lane group {l15 + 16*quad}. Derivation (verified cell-by-cell):
// writer quad q' holds tile ni keys ni*16+q'*4+{0..3} as bf16x2 regs
// w[ni][0] (+0,+1), w[ni][1] (+2,+3). Reader quad q, k-chunk kc needs keys
// kc*32+q*8+{0..7} = tile 2kc+(q>>1), writers 2(q&1) (slots 0,1) and
// 2(q&1)+1 (slots 2,3). Feeding the TILE pair (y=w[2kc][s], z=w[2kc+1][s]):
//   permlane32_swap(y,z): y'=(y@0,y@1,z@0,z@1), z'=(y@2,y@3,z@2,z@3)
//   permlane16_swap(y',z'): y''=(y@0,y@2,z@0,z@2), z''=(y@1,y@3,z@1,z@3)
// y'' == slot-lo operand, z'' == slot-hi operand for every reader quad.
// (Round-1 bug: pre-selecting by the lane's own quad>>1 before the swaps
// served readers q=0,3 correctly but swapped tiles for q=1,2 — absmax 1.44.)
// Cuts LDS 51200 -> 32768 B (3 -> 4 blocks/CU; 1024 blocks = one resident
// round at 4/CU) and removes the ds_write->lgkmcnt(0)->ds_read chain from the
// per-iteration critical path.
__device__ __forceinline__ short8 mk8(uint32_t a, uint32_t b, uint32_t c, uint32_t d) {
  union { uint32_t u[4]; short8 s; } t;
  t.u[0] = a; t.u[1] = b; t.u[2] = c; t.u[3] = d;
  return t.s;
}

__device__ __forceinline__ void softmax_reg(
    const floatx4 (&st)[4], float& lp, uint32_t (&w)[4][2]) {
#pragma unroll
  for (int ni = 0; ni < 4; ++ni) {
    const float p0 = __builtin_amdgcn_exp2f(st[ni][0]);
    const float p1 = __builtin_amdgcn_exp2f(st[ni][1]);
    const float p2 = __builtin_amdgcn_exp2f(st[ni][2]);
    const float p3 = __builtin_amdgcn_exp2f(st[ni][3]);
    lp += (p0 + p1) + (p2 + p3);
    // bf16x2 packets: w[ni][0] = keys(ni*16+quad*4 +0,+1), w[ni][1] = (+2,+3)
    w[ni][0] = __builtin_amdgcn_perm(__float_as_uint(p1), __float_as_uint(p0), 0x07060302u);
    w[ni][1] = __builtin_amdgcn_perm(__float_as_uint(p3), __float_as_uint(p2), 0x07060302u);
  }
}

__device__ __forceinline__ void pv_reg(
    floatx4 (&acc)[4], const uint32_t (&w)[4][2], const short8 (&vf)[2][4]) {
#pragma unroll
  for (int kc = 0; kc < 2; ++kc) {
    // slot s=0: keys +0,+1 of each writer quad; s=1: keys +2,+3.
    uint32_t y0 = w[2 * kc][0], z0 = w[2 * kc + 1][0];
    asm("v_permlane32_swap_b32 %0, %1" : "+v"(y0), "+v"(z0));
    asm("v_permlane16_swap_b32 %0, %1" : "+v"(y0), "+v"(z0));
    uint32_t y1 = w[2 * kc][1], z1 = w[2 * kc + 1][1];
    asm("v_permlane32_swap_b32 %0, %1" : "+v"(y1), "+v"(z1));
    asm("v_permlane16_swap_b32 %0, %1" : "+v"(y1), "+v"(z1));
    // pf = keys kc*32 + quad*8 + {0..7} at q=l15
    const short8 pf = mk8(y0, y1, z0, z1);
#pragma unroll
    for (int di = 0; di < 4; ++di)
      acc[di] = mfma16(pf, vf[kc][di], acc[di]);
  }
}

__global__ __launch_bounds__(256, 4) void k_attn(
    const u16* __restrict__ Q, const u16* __restrict__ Kg,
    const u16* __restrict__ Vt, u16* __restrict__ O) {
  __shared__ __align__(16) u16 Ks[2][64 * 64];
  __shared__ __align__(16) u16 Vs[2][64 * 64];
  const int tid = threadIdx.x, lane = tid & 63, wave = tid >> 6;
  const int quad = lane >> 4, l15 = lane & 15;
  const int bh = blockIdx.y, b = bh >> 4, h = bh & 15;
  const int p = blockIdx.x;                  // pair index 0..15
  const int qwA = 64 * p + wave * 16;
  const int qwB = SEQQ - 64 * (p + 1) + wave * 16;
  const int nT = 32 - p;                     // k-tiles for B (>= A's p+1)

  const u16* kbase = Kg + (size_t)(b * SEQQ) * D_MODEL + h * HDIM;
  const u16* vbase = Vt + (size_t)bh * (HDIM * SEQQ);

  const int srow = tid >> 3;                            // 0..31
  const int scol = ((tid & 7) * 8) ^ ((srow & 7) * 8);  // swizzled col 0..63

  // issue first staging before anything else
  {
    load_lds16(kbase + (size_t)srow * D_MODEL + scol,        &Ks[0][wave * 512]);
    load_lds16(kbase + (size_t)(32 + srow) * D_MODEL + scol, &Ks[0][2048 + wave * 512]);
    load_lds16(vbase + (size_t)srow * SEQQ + scol,           &Vs[0][wave * 512]);
    load_lds16(vbase + (size_t)(32 + srow) * SEQQ + scol,    &Vs[0][2048 + wave * 512]);
  }

  // Q fragments ([idx=l15][k=quad*8+j]); Q pre-scaled by 1/sqrt(hd)*log2e.
  short8 qfA[2], qfB[2];
  {
    const u16* qa = Q + (size_t)(b * SEQQ + qwA + l15) * D_MODEL + h * HDIM;
    const u16* qb = Q + (size_t)(b * SEQQ + qwB + l15) * D_MODEL + h * HDIM;
#pragma unroll
    for (int ks = 0; ks < 2; ++ks) {
      qfA[ks] = *(const short8*)(qa + ks * 32 + quad * 8);
      qfB[ks] = *(const short8*)(qb + ks * 32 + quad * 8);
    }
  }

  floatx4 accA[4], accB[4];
  float lAp = 0.f, lBp = 0.f;     // per-lane partial softmax denominators
#pragma unroll
  for (int i = 0; i < 4; ++i) {
    accA[i] = (floatx4){0.f, 0.f, 0.f, 0.f};
    accB[i] = (floatx4){0.f, 0.f, 0.f, 0.f};
  }

  for (int t = 0; t < nT; ++t) {
    const int cur = t & 1;
    __syncthreads();   // drains stage(t) (vmcnt) + all reads of buf[cur^1]
    if (t + 1 < nT) {  // prefetch next tile into the other buffer
      const int kt1 = (t + 1) * 64, nxt = cur ^ 1;
      load_lds16(kbase + (size_t)(kt1 + srow) * D_MODEL + scol,      &Ks[nxt][wave * 512]);
      load_lds16(kbase + (size_t)(kt1 + 32 + srow) * D_MODEL + scol, &Ks[nxt][2048 + wave * 512]);
      load_lds16(vbase + (size_t)srow * SEQQ + kt1 + scol,           &Vs[nxt][wave * 512]);
      load_lds16(vbase + (size_t)(32 + srow) * SEQQ + kt1 + scol,    &Vs[nxt][2048 + wave * 512]);
    }
    const int kt = t * 64;

    // K fragments ([key=l15][d=quad*8+j]), shared by both q-tiles
    short8 kf[4][2];
#pragma unroll
    for (int ni = 0; ni < 4; ++ni)
#pragma unroll
      for (int ks = 0; ks < 2; ++ks)
        kf[ni][ks] = *(const short8*)&Ks[cur][(ni * 16 + l15) * 64 +
                                            ((ks * 32 + quad * 8) ^ ((l15 & 7) * 8))];
    // V fragments ([d=l15][key=quad*8+j]), shared by both q-tiles
    short8 vf[2][4];
#pragma unroll
    for (int kc = 0; kc < 2; ++kc)
#pragma unroll
      for (int di = 0; di < 4; ++di)
        vf[kc][di] = *(const short8*)&Vs[cur][(di * 16 + l15) * 64 +
                                             ((kc * 32 + quad * 8) ^ ((l15 & 7) * 8))];

    uint32_t wA[4][2], wB[4][2];
    const bool doA = (t <= p);   // block-uniform
    if (doA) {
      floatx4 st[4];   // S^T: row=key (quad*4+r, tile ni), col=q (l15)
#pragma unroll
      for (int ni = 0; ni < 4; ++ni) {
        floatx4 s = (floatx4){0.f, 0.f, 0.f, 0.f};
        s = mfma16(kf[ni][0], qfA[0], s);
        s = mfma16(kf[ni][1], qfA[1], s);
        st[ni] = s;
      }
      if (t == p) {   // diagonal tile of A: mask key > q
        const int qg = qwA + l15;
#pragma unroll
        for (int ni = 0; ni < 4; ++ni) {
          const int kg = kt + ni * 16 + quad * 4;
#pragma unroll
          for (int r = 0; r < 4; ++r)
            if (kg + r > qg) st[ni][r] = -1e30f;
        }
      }
      softmax_reg(st, lAp, wA);
    }
    {
      floatx4 st[4];
#pragma unroll
      for (int ni = 0; ni < 4; ++ni) {
        floatx4 s = (floatx4){0.f, 0.f, 0.f, 0.f};
        s = mfma16(kf[ni][0], qfB[0], s);
        s = mfma16(kf[ni][1], qfB[1], s);
        st[ni] = s;
      }
      if (t == nT - 1) {   // diagonal tile of B
        const int qg = qwB + l15;
#pragma unroll
        for (int ni = 0; ni < 4; ++ni) {
          const int kg = kt + ni * 16 + quad * 4;
#pragma unroll
          for (int r = 0; r < 4; ++r)
            if (kg + r > qg) st[ni][r] = -1e30f;
        }
      }
      softmax_reg(st, lBp, wB);
    }
    if (doA) pv_reg(accA, wA, vf);
    pv_reg(accB, wB, vf);
  }

  // l reduce: across the 4 quad groups (same l15) -> every lane holds l(q=l15)
  lAp += __shfl_xor(lAp, 16); lAp += __shfl_xor(lAp, 32);
  lBp += __shfl_xor(lBp, 16); lBp += __shfl_xor(lBp, 32);

  // epilogue: O rows q=quad*4+r, cols d=di*16+l15; l for row via shfl
  {
    u16* orow = O + (size_t)(b * SEQQ + qwA + quad * 4) * D_MODEL + h * HDIM + l15;
#pragma unroll
    for (int r = 0; r < 4; ++r) {
      const float inv = 1.0f / __shfl(lAp, quad * 4 + r, 16);
#pragma unroll
      for (int di = 0; di < 4; ++di)
        orow[(size_t)r * D_MODEL + di * 16] = f2bf(accA[di][r] * inv);
    }
  }
  {
    u16* orow = O + (size_t)(b * SEQQ + qwB + quad * 4) * D_MODEL + h * HDIM + l15;
#pragma unroll
    for (int r = 0; r < 4; ++r) {
      const float inv = 1.0f / __shfl(lBp, quad * 4 + r, 16);
#pragma unroll
      for (int di = 0; di < 4; ++di)
        orow[(size_t)r * D_MODEL + di * 16] = f2bf(accB[di][r] * inv);
    }
  }
}

// ---------------------------------------------------------------- launch
extern "C" void kernel_launch(void* const* d_in, const int* in_sizes, int n_in,
                              void* d_out, int out_size, void* d_ws, size_t ws_size,
                              hipStream_t stream) {
  const float* X  = (const float*)d_in[0];
  const float* Wq = (const float*)d_in[1];
  const float* Wk = (const float*)d_in[2];
  const float* Wv = (const float*)d_in[3];
  const float* Wo = (const float*)d_in[4];
  const float* bo = (const float*)d_in[5];
  float* out = (float*)d_out;

  u16* ws = (u16*)d_ws;
  const size_t NE = (size_t)MTOT * D_MODEL;    // 8,388,608
  u16* Xb  = ws;
  u16* Qb  = Xb + NE;
  u16* Kb  = Qb + NE;
  u16* Vt  = Kb + NE;          // V projection written directly transposed
  u16* Cb  = Vt + NE;
  u16* Wqb = Cb + NE;
  u16* Wkb = Wqb + (size_t)D_MODEL * D_MODEL;
  u16* Wvb = Wkb + (size_t)D_MODEL * D_MODEL;
  u16* Wob = Wvb + (size_t)D_MODEL * D_MODEL;

  const float SCL2E = 0.18033688f;   // (1/sqrt(64)) * log2(e), folded into Q

  // 1. all casts in one launch
  k_cast_all<<<12288, 256, 0, stream>>>(X, Wq, Wk, Wv, Wo, Xb, Wqb, Wkb, Wvb, Wob);

  // 2. fused QKV projections (Q pre-scaled; V written transposed into Vt)
  k_gemm_bt<<<dim3(D_MODEL / 128, MTOT / 128, 3), 256, 0, stream>>>(
      Xb, Wqb, Wkb, Wvb, Qb, Kb, Vt, nullptr, MTOT, D_MODEL, D_MODEL, 0, SCL2E);

  // 3. causal flash attention, paired 64-row q-tiles -> Cb [8192][1024]
  k_attn<<<dim3(16, NBATCH * NHEAD), 256, 0, stream>>>(Qb, Kb, Vt, Cb);

  // 4. output projection + bias, f32 out
  k_gemm_bt<<<dim3(D_MODEL / 128, MTOT / 128, 1), 256, 0, stream>>>(
      Cb, Wob, Wob, Wob, out, out, nullptr, bo, MTOT, D_MODEL, D_MODEL, 1, 1.0f);
}

// Round 3
// 301.358 us; speedup vs baseline: 1.3523x; 1.3523x over previous
//
#include <hip/hip_runtime.h>
#include <cstdint>
#include <cstddef>

// Problem constants (MultiHeadAttention: B=4, T=2048, d_model=1024, H=16, hd=64)
#define D_MODEL 1024
#define SEQQ    2048
#define NBATCH  4
#define NHEAD   16
#define HDIM    64
#define MTOT    (NBATCH * SEQQ)   // 8192 rows

typedef __attribute__((ext_vector_type(8))) short short8;   // 8 x bf16 (4 VGPRs) — MFMA A/B frag
typedef __attribute__((ext_vector_type(4))) float floatx4;  // MFMA C/D frag
typedef unsigned short u16;                                  // bf16 bits

__device__ __forceinline__ u16 f2bf(float f) {
  union { float f; uint32_t u; } a; a.f = f;
  uint32_t u = a.u;
  u += 0x7fffu + ((u >> 16) & 1u);   // RN-even
  return (u16)(u >> 16);
}

__device__ __forceinline__ floatx4 mfma16(short8 a, short8 b, floatx4 c) {
  return __builtin_amdgcn_mfma_f32_16x16x32_bf16(a, b, c, 0, 0, 0);
}

// async global->LDS, 16B per lane. LDS dest = wave-uniform base + lane*16.
__device__ __forceinline__ void load_lds16(const void* g, void* l) {
  __builtin_amdgcn_global_load_lds(
      (const __attribute__((address_space(1))) uint32_t*)g,
      (__attribute__((address_space(3))) uint32_t*)l, 16, 0, 0);
}

// ---------------------------------------------------------------- fused casts f32->bf16
// blocks [0, 8192): X. blocks [8192, 12288): weights, 1024 blocks each.
__global__ __launch_bounds__(256) void k_cast_all(
    const float* __restrict__ X, const float* __restrict__ w0,
    const float* __restrict__ w1, const float* __restrict__ w2,
    const float* __restrict__ w3,
    u16* __restrict__ xb, u16* __restrict__ y0, u16* __restrict__ y1,
    u16* __restrict__ y2, u16* __restrict__ y3) {
  const int bx = blockIdx.x;
  const float* src; u16* dst; int i;
  if (bx < 8192) {
    src = X; dst = xb; i = (bx * 256 + threadIdx.x) * 4;
  } else {
    const int w = (bx - 8192) >> 10;
    src = (w == 0) ? w0 : (w == 1) ? w1 : (w == 2) ? w2 : w3;
    dst = (w == 0) ? y0 : (w == 1) ? y1 : (w == 2) ? y2 : y3;
    i = (((bx - 8192) & 1023) * 256 + threadIdx.x) * 4;
  }
  float4 v = *(const float4*)(src + i);
  ushort4 o;
  o.x = f2bf(v.x); o.y = f2bf(v.y); o.z = f2bf(v.z); o.w = f2bf(v.w);
  *(ushort4*)(dst + i) = o;
}

// ---------------------------------------------------------------- GEMM  C = A @ B^T (+bias)
// ascaleQ: extra scale on the z==0 output (folds 1/sqrt(hd)*log2e into Q).
// z==2 (V projection): epilogue writes TRANSPOSED into Vt [bh][64][2048].
__global__ __launch_bounds__(256) void k_gemm_bt(
    const u16* __restrict__ A,
    const u16* __restrict__ B0, const u16* __restrict__ B1, const u16* __restrict__ B2,
    void* __restrict__ C0, void* __restrict__ C1, u16* __restrict__ VtOut,
    const float* __restrict__ bias, int M, int N, int K, int f32out, float ascaleQ) {
  __shared__ __align__(16) u16 As[128 * 64];
  __shared__ __align__(16) u16 Bs[128 * 64];
  const int tid = threadIdx.x;
  const int lane = tid & 63, wave = tid >> 6;
  const int quad = lane >> 4, l15 = lane & 15;
  const int m0 = blockIdx.y * 128, n0 = blockIdx.x * 128;
  const int wr = wave >> 1, wc = wave & 1;
  const u16* Bm = (blockIdx.z == 0) ? B0 : (blockIdx.z == 1 ? B1 : B2);
  void* Cm = (blockIdx.z == 0) ? C0 : C1;
  const float ascale = (blockIdx.z == 0) ? ascaleQ : 1.0f;

  floatx4 acc[4][4];
#pragma unroll
  for (int i = 0; i < 4; ++i)
#pragma unroll
    for (int j = 0; j < 4; ++j) acc[i][j] = (floatx4){0.f, 0.f, 0.f, 0.f};

  const int srow = tid >> 3;                       // 0..31
  const int scolx = ((tid & 7) * 8) ^ ((srow & 7) * 8);  // swizzled source column
  const u16* Ag = A + (size_t)(m0 + srow) * K + scolx;
  const u16* Bg = Bm + (size_t)(n0 + srow) * K + scolx;

  for (int kt = 0; kt < K; kt += 64) {
    __syncthreads();
#pragma unroll
    for (int p = 0; p < 4; ++p) {
      load_lds16(Ag + (size_t)(p * 32) * K + kt, &As[p * 2048 + wave * 512]);
      load_lds16(Bg + (size_t)(p * 32) * K + kt, &Bs[p * 2048 + wave * 512]);
    }
    __syncthreads();

    short8 af[2][4], bfg[2][4];
#pragma unroll
    for (int ks = 0; ks < 2; ++ks) {
      const int kkx = (ks * 32 + quad * 8) ^ ((l15 & 7) * 8);
#pragma unroll
      for (int i = 0; i < 4; ++i) {
        af[ks][i]  = *(const short8*)&As[(wr * 64 + i * 16 + l15) * 64 + kkx];
        bfg[ks][i] = *(const short8*)&Bs[(wc * 64 + i * 16 + l15) * 64 + kkx];
      }
    }
#pragma unroll
    for (int ks = 0; ks < 2; ++ks)
#pragma unroll
      for (int mi = 0; mi < 4; ++mi)
#pragma unroll
        for (int ni = 0; ni < 4; ++ni)
          acc[mi][ni] = mfma16(af[ks][mi], bfg[ks][ni], acc[mi][ni]);
  }

  // Epilogue. C/D layout: col = lane&15, row = quad*4 + reg (m89-verified).
  if (blockIdx.z == 2) {
    // transposed V write: Vt[(b*16+h)*64 + d][t], 4 regs = t..t+3 contiguous
#pragma unroll
    for (int mi = 0; mi < 4; ++mi) {
#pragma unroll
      for (int ni = 0; ni < 4; ++ni) {
        const int row = m0 + wr * 64 + mi * 16 + quad * 4;   // token
        const int col = n0 + wc * 64 + ni * 16 + l15;        // channel
        const int b = row >> 11, t = row & 2047;
        const int h = col >> 6, d = col & 63;
        ushort4 pk;
        pk.x = f2bf(acc[mi][ni][0]); pk.y = f2bf(acc[mi][ni][1]);
        pk.z = f2bf(acc[mi][ni][2]); pk.w = f2bf(acc[mi][ni][3]);
        *(ushort4*)(VtOut + (((size_t)(b * 16 + h) * 64 + d) * SEQQ + t)) = pk;
      }
    }
    return;
  }
#pragma unroll
  for (int mi = 0; mi < 4; ++mi) {
#pragma unroll
    for (int ni = 0; ni < 4; ++ni) {
      const int row = m0 + wr * 64 + mi * 16 + quad * 4;
      const int col = n0 + wc * 64 + ni * 16 + l15;
      const float bv = bias ? bias[col] : 0.f;
#pragma unroll
      for (int r = 0; r < 4; ++r) {
        const float v = acc[mi][ni][r] * ascale + bv;
        if (f32out) ((float*)Cm)[(size_t)(row + r) * N + col] = v;
        else        ((u16*)Cm)[(size_t)(row + r) * N + col] = f2bf(v);
      }
    }
  }
}

// ---------------------------------------------------------------- flash attention
// r4/r6 structure (paired q-tiles (p,31-p), 64-row granularity, 4 waves x 16 q),
// double-buffered K/V staging, ONE barrier per iteration.
// P redistribution (S^T -> PV A-operand) fully in registers via
// v_permlane32_swap_b32 + v_permlane16_swap_b32 (derivation verified in r2 —
// feed the TILE pair (y=w[2kc][s], z=w[2kc+1][s]) into the swap network; the
// two outputs are the slot-lo / slot-hi PV operand words for every quad).
// ROUND-2 POST-MORTEM: __launch_bounds__(256,4) forced the allocator to 64
// VGPRs -> ~800 MB of scratch spill traffic (WRITE_SIZE 16->410 MB), 2.2x
// slower. Fix here: plain launch_bounds(256) + STRUCTURAL pressure reduction:
//  - QK^T per-ni: K fragments live 8 regs at a time (was 32)
//  - PV per-kc:   V fragments live 16 regs at a time (was 32), shared by A/B
//  - st dies per-ni (8 live, was 32)
// Target natural usage ~100-110 VGPR -> 4+ waves/EU occupancy without spill.
__device__ __forceinline__ short8 mk8(uint32_t a, uint32_t b, uint32_t c, uint32_t d) {
  union { uint32_t u[4]; short8 s; } t;
  t.u[0] = a; t.u[1] = b; t.u[2] = c; t.u[3] = d;
  return t.s;
}

// exp2 + pack one 16x16 S^T tile's 4 values -> denominator + 2 bf16x2 words
__device__ __forceinline__ void softmax_ni(
    const floatx4& s, float& lp, uint32_t (&w)[2]) {
  const float p0 = __builtin_amdgcn_exp2f(s[0]);
  const float p1 = __builtin_amdgcn_exp2f(s[1]);
  const float p2 = __builtin_amdgcn_exp2f(s[2]);
  const float p3 = __builtin_amdgcn_exp2f(s[3]);
  lp += (p0 + p1) + (p2 + p3);
  // w[0] = keys(ni*16+quad*4 +0,+1), w[1] = (+2,+3), packed bf16x2
  w[0] = __builtin_amdgcn_perm(__float_as_uint(p1), __float_as_uint(p0), 0x07060302u);
  w[1] = __builtin_amdgcn_perm(__float_as_uint(p3), __float_as_uint(p2), 0x07060302u);
}

// build PV A-operand (keys kc*32+quad*8+{0..7} at q=l15) from the 4 quads'
// packed tiles via the quad-transpose swap network.
__device__ __forceinline__ short8 pf_prep(const uint32_t (&w)[4][2], int kc) {
  uint32_t y0 = w[2 * kc][0], z0 = w[2 * kc + 1][0];
  asm("v_permlane32_swap_b32 %0, %1" : "+v"(y0), "+v"(z0));
  asm("v_permlane16_swap_b32 %0, %1" : "+v"(y0), "+v"(z0));
  uint32_t y1 = w[2 * kc][1], z1 = w[2 * kc + 1][1];
  asm("v_permlane32_swap_b32 %0, %1" : "+v"(y1), "+v"(z1));
  asm("v_permlane16_swap_b32 %0, %1" : "+v"(y1), "+v"(z1));
  return mk8(y0, y1, z0, z1);
}

__global__ __launch_bounds__(256) void k_attn(
    const u16* __restrict__ Q, const u16* __restrict__ Kg,
    const u16* __restrict__ Vt, u16* __restrict__ O) {
  __shared__ __align__(16) u16 Ks[2][64 * 64];
  __shared__ __align__(16) u16 Vs[2][64 * 64];
  const int tid = threadIdx.x, lane = tid & 63, wave = tid >> 6;
  const int quad = lane >> 4, l15 = lane & 15;
  const int bh = blockIdx.y, b = bh >> 4, h = bh & 15;
  const int p = blockIdx.x;                  // pair index 0..15
  const int qwA = 64 * p + wave * 16;
  const int qwB = SEQQ - 64 * (p + 1) + wave * 16;
  const int nT = 32 - p;                     // k-tiles for B (>= A's p+1)

  const u16* kbase = Kg + (size_t)(b * SEQQ) * D_MODEL + h * HDIM;
  const u16* vbase = Vt + (size_t)bh * (HDIM * SEQQ);

  const int srow = tid >> 3;                            // 0..31
  const int scol = ((tid & 7) * 8) ^ ((srow & 7) * 8);  // swizzled col 0..63

  // issue first staging before anything else
  {
    load_lds16(kbase + (size_t)srow * D_MODEL + scol,        &Ks[0][wave * 512]);
    load_lds16(kbase + (size_t)(32 + srow) * D_MODEL + scol, &Ks[0][2048 + wave * 512]);
    load_lds16(vbase + (size_t)srow * SEQQ + scol,           &Vs[0][wave * 512]);
    load_lds16(vbase + (size_t)(32 + srow) * SEQQ + scol,    &Vs[0][2048 + wave * 512]);
  }

  // Q fragments ([idx=l15][k=quad*8+j]); Q pre-scaled by 1/sqrt(hd)*log2e.
  short8 qfA[2], qfB[2];
  {
    const u16* qa = Q + (size_t)(b * SEQQ + qwA + l15) * D_MODEL + h * HDIM;
    const u16* qb = Q + (size_t)(b * SEQQ + qwB + l15) * D_MODEL + h * HDIM;
#pragma unroll
    for (int ks = 0; ks < 2; ++ks) {
      qfA[ks] = *(const short8*)(qa + ks * 32 + quad * 8);
      qfB[ks] = *(const short8*)(qb + ks * 32 + quad * 8);
    }
  }

  floatx4 accA[4], accB[4];
  float lAp = 0.f, lBp = 0.f;     // per-lane partial softmax denominators
#pragma unroll
  for (int i = 0; i < 4; ++i) {
    accA[i] = (floatx4){0.f, 0.f, 0.f, 0.f};
    accB[i] = (floatx4){0.f, 0.f, 0.f, 0.f};
  }

  const int swz = (l15 & 7) * 8;   // per-lane LDS XOR swizzle term

  for (int t = 0; t < nT; ++t) {
    const int cur = t & 1;
    __syncthreads();   // drains stage(t) (vmcnt) + all reads of buf[cur^1]
    if (t + 1 < nT) {  // prefetch next tile into the other buffer
      const int kt1 = (t + 1) * 64, nxt = cur ^ 1;
      load_lds16(kbase + (size_t)(kt1 + srow) * D_MODEL + scol,      &Ks[nxt][wave * 512]);
      load_lds16(kbase + (size_t)(kt1 + 32 + srow) * D_MODEL + scol, &Ks[nxt][2048 + wave * 512]);
      load_lds16(vbase + (size_t)srow * SEQQ + kt1 + scol,           &Vs[nxt][wave * 512]);
      load_lds16(vbase + (size_t)(32 + srow) * SEQQ + kt1 + scol,    &Vs[nxt][2048 + wave * 512]);
    }
    const int kt = t * 64;
    const bool doA = (t <= p);   // block-uniform

    uint32_t wA[4][2], wB[4][2];
    // ---- QK^T + softmax, per-ni so K fragments/st die fast ----
#pragma unroll
    for (int ni = 0; ni < 4; ++ni) {
      const int krow = (ni * 16 + l15) * 64;
      const short8 k0 = *(const short8*)&Ks[cur][krow + ((quad * 8) ^ swz)];
      const short8 k1 = *(const short8*)&Ks[cur][krow + ((32 + quad * 8) ^ swz)];
      if (doA) {
        floatx4 s = (floatx4){0.f, 0.f, 0.f, 0.f};
        s = mfma16(k0, qfA[0], s);
        s = mfma16(k1, qfA[1], s);
        if (t == p) {   // diagonal tile of A: mask key > q
          const int qg = qwA + l15;
          const int kg = kt + ni * 16 + quad * 4;
#pragma unroll
          for (int r = 0; r < 4; ++r)
            if (kg + r > qg) s[r] = -1e30f;
        }
        softmax_ni(s, lAp, wA[ni]);
      }
      {
        floatx4 s = (floatx4){0.f, 0.f, 0.f, 0.f};
        s = mfma16(k0, qfB[0], s);
        s = mfma16(k1, qfB[1], s);
        if (t == nT - 1) {   // diagonal tile of B
          const int qg = qwB + l15;
          const int kg = kt + ni * 16 + quad * 4;
#pragma unroll
          for (int r = 0; r < 4; ++r)
            if (kg + r > qg) s[r] = -1e30f;
        }
        softmax_ni(s, lBp, wB[ni]);
      }
    }

    // ---- PV, per-kc so V fragments die fast; vf shared by A and B ----
#pragma unroll
    for (int kc = 0; kc < 2; ++kc) {
      short8 vf[4];
#pragma unroll
      for (int di = 0; di < 4; ++di)
        vf[di] = *(const short8*)&Vs[cur][(di * 16 + l15) * 64 +
                                          ((kc * 32 + quad * 8) ^ swz)];
      short8 pfB = pf_prep(wB, kc);
      if (doA) {
        const short8 pfA = pf_prep(wA, kc);
#pragma unroll
        for (int di = 0; di < 4; ++di)
          accA[di] = mfma16(pfA, vf[di], accA[di]);
      }
#pragma unroll
      for (int di = 0; di < 4; ++di)
        accB[di] = mfma16(pfB, vf[di], accB[di]);
    }
  }

  // l reduce: across the 4 quad groups (same l15) -> every lane holds l(q=l15)
  lAp += __shfl_xor(lAp, 16); lAp += __shfl_xor(lAp, 32);
  lBp += __shfl_xor(lBp, 16); lBp += __shfl_xor(lBp, 32);

  // epilogue: O rows q=quad*4+r, cols d=di*16+l15; l for row via shfl
  {
    u16* orow = O + (size_t)(b * SEQQ + qwA + quad * 4) * D_MODEL + h * HDIM + l15;
#pragma unroll
    for (int r = 0; r < 4; ++r) {
      const float inv = 1.0f / __shfl(lAp, quad * 4 + r, 16);
#pragma unroll
      for (int di = 0; di < 4; ++di)
        orow[(size_t)r * D_MODEL + di * 16] = f2bf(accA[di][r] * inv);
    }
  }
  {
    u16* orow = O + (size_t)(b * SEQQ + qwB + quad * 4) * D_MODEL + h * HDIM + l15;
#pragma unroll
    for (int r = 0; r < 4; ++r) {
      const float inv = 1.0f / __shfl(lBp, quad * 4 + r, 16);
#pragma unroll
      for (int di = 0; di < 4; ++di)
        orow[(size_t)r * D_MODEL + di * 16] = f2bf(accB[di][r] * inv);
    }
  }
}

// ---------------------------------------------------------------- launch
extern "C" void kernel_launch(void* const* d_in, const int* in_sizes, int n_in,
                              void* d_out, int out_size, void* d_ws, size_t ws_size,
                              hipStream_t stream) {
  const float* X  = (const float*)d_in[0];
  const float* Wq = (const float*)d_in[1];
  const float* Wk = (const float*)d_in[2];
  const float* Wv = (const float*)d_in[3];
  const float* Wo = (const float*)d_in[4];
  const float* bo = (const float*)d_in[5];
  float* out = (float*)d_out;

  u16* ws = (u16*)d_ws;
  const size_t NE = (size_t)MTOT * D_MODEL;    // 8,388,608
  u16* Xb  = ws;
  u16* Qb  = Xb + NE;
  u16* Kb  = Qb + NE;
  u16* Vt  = Kb + NE;          // V projection written directly transposed
  u16* Cb  = Vt + NE;
  u16* Wqb = Cb + NE;
  u16* Wkb = Wqb + (size_t)D_MODEL * D_MODEL;
  u16* Wvb = Wkb + (size_t)D_MODEL * D_MODEL;
  u16* Wob = Wvb + (size_t)D_MODEL * D_MODEL;

  const float SCL2E = 0.18033688f;   // (1/sqrt(64)) * log2(e), folded into Q

  // 1. all casts in one launch
  k_cast_all<<<12288, 256, 0, stream>>>(X, Wq, Wk, Wv, Wo, Xb, Wqb, Wkb, Wvb, Wob);

  // 2. fused QKV projections (Q pre-scaled; V written transposed into Vt)
  k_gemm_bt<<<dim3(D_MODEL / 128, MTOT / 128, 3), 256, 0, stream>>>(
      Xb, Wqb, Wkb, Wvb, Qb, Kb, Vt, nullptr, MTOT, D_MODEL, D_MODEL, 0, SCL2E);

  // 3. causal flash attention, paired 64-row q-tiles -> Cb [8192][1024]
  k_attn<<<dim3(16, NBATCH * NHEAD), 256, 0, stream>>>(Qb, Kb, Vt, Cb);

  // 4. output projection + bias, f32 out
  k_gemm_bt<<<dim3(D_MODEL / 128, MTOT / 128, 1), 256, 0, stream>>>(
      Cb, Wob, Wob, Wob, out, out, nullptr, bo, MTOT, D_MODEL, D_MODEL, 1, 1.0f);
}

// Round 4
// 294.214 us; speedup vs baseline: 1.3852x; 1.0243x over previous
//
#include <hip/hip_runtime.h>
#include <cstdint>
#include <cstddef>

// Problem constants (MultiHeadAttention: B=4, T=2048, d_model=1024, H=16, hd=64)
#define D_MODEL 1024
#define SEQQ    2048
#define NBATCH  4
#define NHEAD   16
#define HDIM    64
#define MTOT    (NBATCH * SEQQ)   // 8192 rows

typedef __attribute__((ext_vector_type(8))) short short8;   // 8 x bf16 (4 VGPRs) — MFMA A/B frag
typedef __attribute__((ext_vector_type(4))) float floatx4;  // MFMA C/D frag
typedef unsigned short u16;                                  // bf16 bits

__device__ __forceinline__ u16 f2bf(float f) {
  union { float f; uint32_t u; } a; a.f = f;
  uint32_t u = a.u;
  u += 0x7fffu + ((u >> 16) & 1u);   // RN-even
  return (u16)(u >> 16);
}

__device__ __forceinline__ floatx4 mfma16(short8 a, short8 b, floatx4 c) {
  return __builtin_amdgcn_mfma_f32_16x16x32_bf16(a, b, c, 0, 0, 0);
}

// async global->LDS, 16B per lane. LDS dest = wave-uniform base + lane*16.
__device__ __forceinline__ void load_lds16(const void* g, void* l) {
  __builtin_amdgcn_global_load_lds(
      (const __attribute__((address_space(1))) uint32_t*)g,
      (__attribute__((address_space(3))) uint32_t*)l, 16, 0, 0);
}

// ---------------------------------------------------------------- fused casts f32->bf16
// blocks [0, 8192): X. blocks [8192, 12288): weights, 1024 blocks each.
__global__ __launch_bounds__(256) void k_cast_all(
    const float* __restrict__ X, const float* __restrict__ w0,
    const float* __restrict__ w1, const float* __restrict__ w2,
    const float* __restrict__ w3,
    u16* __restrict__ xb, u16* __restrict__ y0, u16* __restrict__ y1,
    u16* __restrict__ y2, u16* __restrict__ y3) {
  const int bx = blockIdx.x;
  const float* src; u16* dst; int i;
  if (bx < 8192) {
    src = X; dst = xb; i = (bx * 256 + threadIdx.x) * 4;
  } else {
    const int w = (bx - 8192) >> 10;
    src = (w == 0) ? w0 : (w == 1) ? w1 : (w == 2) ? w2 : w3;
    dst = (w == 0) ? y0 : (w == 1) ? y1 : (w == 2) ? y2 : y3;
    i = (((bx - 8192) & 1023) * 256 + threadIdx.x) * 4;
  }
  float4 v = *(const float4*)(src + i);
  ushort4 o;
  o.x = f2bf(v.x); o.y = f2bf(v.y); o.z = f2bf(v.z); o.w = f2bf(v.w);
  *(ushort4*)(dst + i) = o;
}

// ---------------------------------------------------------------- GEMM  C = A @ B^T (+bias)
// ascaleQ: extra scale on the z==0 output (folds 1/sqrt(hd)*log2e into Q).
// z==2 (V projection): epilogue writes TRANSPOSED into Vt [bh][64][2048].
__global__ __launch_bounds__(256) void k_gemm_bt(
    const u16* __restrict__ A,
    const u16* __restrict__ B0, const u16* __restrict__ B1, const u16* __restrict__ B2,
    void* __restrict__ C0, void* __restrict__ C1, u16* __restrict__ VtOut,
    const float* __restrict__ bias, int M, int N, int K, int f32out, float ascaleQ) {
  __shared__ __align__(16) u16 As[128 * 64];
  __shared__ __align__(16) u16 Bs[128 * 64];
  const int tid = threadIdx.x;
  const int lane = tid & 63, wave = tid >> 6;
  const int quad = lane >> 4, l15 = lane & 15;
  const int m0 = blockIdx.y * 128, n0 = blockIdx.x * 128;
  const int wr = wave >> 1, wc = wave & 1;
  const u16* Bm = (blockIdx.z == 0) ? B0 : (blockIdx.z == 1 ? B1 : B2);
  void* Cm = (blockIdx.z == 0) ? C0 : C1;
  const float ascale = (blockIdx.z == 0) ? ascaleQ : 1.0f;

  floatx4 acc[4][4];
#pragma unroll
  for (int i = 0; i < 4; ++i)
#pragma unroll
    for (int j = 0; j < 4; ++j) acc[i][j] = (floatx4){0.f, 0.f, 0.f, 0.f};

  const int srow = tid >> 3;                       // 0..31
  const int scolx = ((tid & 7) * 8) ^ ((srow & 7) * 8);  // swizzled source column
  const u16* Ag = A + (size_t)(m0 + srow) * K + scolx;
  const u16* Bg = Bm + (size_t)(n0 + srow) * K + scolx;

  for (int kt = 0; kt < K; kt += 64) {
    __syncthreads();
#pragma unroll
    for (int p = 0; p < 4; ++p) {
      load_lds16(Ag + (size_t)(p * 32) * K + kt, &As[p * 2048 + wave * 512]);
      load_lds16(Bg + (size_t)(p * 32) * K + kt, &Bs[p * 2048 + wave * 512]);
    }
    __syncthreads();

    short8 af[2][4], bfg[2][4];
#pragma unroll
    for (int ks = 0; ks < 2; ++ks) {
      const int kkx = (ks * 32 + quad * 8) ^ ((l15 & 7) * 8);
#pragma unroll
      for (int i = 0; i < 4; ++i) {
        af[ks][i]  = *(const short8*)&As[(wr * 64 + i * 16 + l15) * 64 + kkx];
        bfg[ks][i] = *(const short8*)&Bs[(wc * 64 + i * 16 + l15) * 64 + kkx];
      }
    }
#pragma unroll
    for (int ks = 0; ks < 2; ++ks)
#pragma unroll
      for (int mi = 0; mi < 4; ++mi)
#pragma unroll
        for (int ni = 0; ni < 4; ++ni)
          acc[mi][ni] = mfma16(af[ks][mi], bfg[ks][ni], acc[mi][ni]);
  }

  // Epilogue. C/D layout: col = lane&15, row = quad*4 + reg (m89-verified).
  if (blockIdx.z == 2) {
    // transposed V write: Vt[(b*16+h)*64 + d][t], 4 regs = t..t+3 contiguous
#pragma unroll
    for (int mi = 0; mi < 4; ++mi) {
#pragma unroll
      for (int ni = 0; ni < 4; ++ni) {
        const int row = m0 + wr * 64 + mi * 16 + quad * 4;   // token
        const int col = n0 + wc * 64 + ni * 16 + l15;        // channel
        const int b = row >> 11, t = row & 2047;
        const int h = col >> 6, d = col & 63;
        ushort4 pk;
        pk.x = f2bf(acc[mi][ni][0]); pk.y = f2bf(acc[mi][ni][1]);
        pk.z = f2bf(acc[mi][ni][2]); pk.w = f2bf(acc[mi][ni][3]);
        *(ushort4*)(VtOut + (((size_t)(b * 16 + h) * 64 + d) * SEQQ + t)) = pk;
      }
    }
    return;
  }
#pragma unroll
  for (int mi = 0; mi < 4; ++mi) {
#pragma unroll
    for (int ni = 0; ni < 4; ++ni) {
      const int row = m0 + wr * 64 + mi * 16 + quad * 4;
      const int col = n0 + wc * 64 + ni * 16 + l15;
      const float bv = bias ? bias[col] : 0.f;
#pragma unroll
      for (int r = 0; r < 4; ++r) {
        const float v = acc[mi][ni][r] * ascale + bv;
        if (f32out) ((float*)Cm)[(size_t)(row + r) * N + col] = v;
        else        ((u16*)Cm)[(size_t)(row + r) * N + col] = f2bf(v);
      }
    }
  }
}

// ---------------------------------------------------------------- flash attention
// r4/r6 structure (paired q-tiles (p,31-p), 64-row granularity, 4 waves x 16 q),
// double-buffered K/V staging, ONE barrier per iteration.
// P redistribution (S^T -> PV A-operand) fully in registers via
// v_permlane32_swap_b32 + v_permlane16_swap_b32 (derivation verified in r2).
// ROUND-3 POST-MORTEM: per-ni K loads / per-kc V loads serialized LDS latency
// (one lgkmcnt wait per fragment pair instead of one batched window) ->
// 94.5 -> 110us. FIX: restore round-0 batched scheduling with permlane kept:
//   - all 8 kf ds_read_b128 issued together BEFORE QK^T (kf dead before PV)
//   - all 8 vf ds_read_b128 issued together AFTER QK^T (vf live only in PV)
// Liveness peaks ~120 VGPR in both phases -> stays under the 128-reg /
// 4-waves-per-SIMD cliff (grid caps at 4 blocks/CU anyway). No forced
// launch_bounds min-occupancy (round-2 spill disaster).
__device__ __forceinline__ short8 mk8(uint32_t a, uint32_t b, uint32_t c, uint32_t d) {
  union { uint32_t u[4]; short8 s; } t;
  t.u[0] = a; t.u[1] = b; t.u[2] = c; t.u[3] = d;
  return t.s;
}

// exp2 + pack one 16x16 S^T tile's 4 values -> denominator + 2 bf16x2 words
__device__ __forceinline__ void softmax_ni(
    const floatx4& s, float& lp, uint32_t (&w)[2]) {
  const float p0 = __builtin_amdgcn_exp2f(s[0]);
  const float p1 = __builtin_amdgcn_exp2f(s[1]);
  const float p2 = __builtin_amdgcn_exp2f(s[2]);
  const float p3 = __builtin_amdgcn_exp2f(s[3]);
  lp += (p0 + p1) + (p2 + p3);
  // w[0] = keys(ni*16+quad*4 +0,+1), w[1] = (+2,+3), packed bf16x2
  w[0] = __builtin_amdgcn_perm(__float_as_uint(p1), __float_as_uint(p0), 0x07060302u);
  w[1] = __builtin_amdgcn_perm(__float_as_uint(p3), __float_as_uint(p2), 0x07060302u);
}

// build PV A-operand (keys kc*32+quad*8+{0..7} at q=l15) from the 4 quads'
// packed tiles via the quad-transpose swap network.
__device__ __forceinline__ short8 pf_prep(const uint32_t (&w)[4][2], int kc) {
  uint32_t y0 = w[2 * kc][0], z0 = w[2 * kc + 1][0];
  asm("v_permlane32_swap_b32 %0, %1" : "+v"(y0), "+v"(z0));
  asm("v_permlane16_swap_b32 %0, %1" : "+v"(y0), "+v"(z0));
  uint32_t y1 = w[2 * kc][1], z1 = w[2 * kc + 1][1];
  asm("v_permlane32_swap_b32 %0, %1" : "+v"(y1), "+v"(z1));
  asm("v_permlane16_swap_b32 %0, %1" : "+v"(y1), "+v"(z1));
  return mk8(y0, y1, z0, z1);
}

__global__ __launch_bounds__(256) void k_attn(
    const u16* __restrict__ Q, const u16* __restrict__ Kg,
    const u16* __restrict__ Vt, u16* __restrict__ O) {
  __shared__ __align__(16) u16 Ks[2][64 * 64];
  __shared__ __align__(16) u16 Vs[2][64 * 64];
  const int tid = threadIdx.x, lane = tid & 63, wave = tid >> 6;
  const int quad = lane >> 4, l15 = lane & 15;
  const int bh = blockIdx.y, b = bh >> 4, h = bh & 15;
  const int p = blockIdx.x;                  // pair index 0..15
  const int qwA = 64 * p + wave * 16;
  const int qwB = SEQQ - 64 * (p + 1) + wave * 16;
  const int nT = 32 - p;                     // k-tiles for B (>= A's p+1)

  const u16* kbase = Kg + (size_t)(b * SEQQ) * D_MODEL + h * HDIM;
  const u16* vbase = Vt + (size_t)bh * (HDIM * SEQQ);

  const int srow = tid >> 3;                            // 0..31
  const int scol = ((tid & 7) * 8) ^ ((srow & 7) * 8);  // swizzled col 0..63

  // issue first staging before anything else
  {
    load_lds16(kbase + (size_t)srow * D_MODEL + scol,        &Ks[0][wave * 512]);
    load_lds16(kbase + (size_t)(32 + srow) * D_MODEL + scol, &Ks[0][2048 + wave * 512]);
    load_lds16(vbase + (size_t)srow * SEQQ + scol,           &Vs[0][wave * 512]);
    load_lds16(vbase + (size_t)(32 + srow) * SEQQ + scol,    &Vs[0][2048 + wave * 512]);
  }

  // Q fragments ([idx=l15][k=quad*8+j]); Q pre-scaled by 1/sqrt(hd)*log2e.
  short8 qfA[2], qfB[2];
  {
    const u16* qa = Q + (size_t)(b * SEQQ + qwA + l15) * D_MODEL + h * HDIM;
    const u16* qb = Q + (size_t)(b * SEQQ + qwB + l15) * D_MODEL + h * HDIM;
#pragma unroll
    for (int ks = 0; ks < 2; ++ks) {
      qfA[ks] = *(const short8*)(qa + ks * 32 + quad * 8);
      qfB[ks] = *(const short8*)(qb + ks * 32 + quad * 8);
    }
  }

  floatx4 accA[4], accB[4];
  float lAp = 0.f, lBp = 0.f;     // per-lane partial softmax denominators
#pragma unroll
  for (int i = 0; i < 4; ++i) {
    accA[i] = (floatx4){0.f, 0.f, 0.f, 0.f};
    accB[i] = (floatx4){0.f, 0.f, 0.f, 0.f};
  }

  const int swz = (l15 & 7) * 8;   // per-lane LDS XOR swizzle term

  for (int t = 0; t < nT; ++t) {
    const int cur = t & 1;
    __syncthreads();   // drains stage(t) (vmcnt) + all reads of buf[cur^1]
    if (t + 1 < nT) {  // prefetch next tile into the other buffer
      const int kt1 = (t + 1) * 64, nxt = cur ^ 1;
      load_lds16(kbase + (size_t)(kt1 + srow) * D_MODEL + scol,      &Ks[nxt][wave * 512]);
      load_lds16(kbase + (size_t)(kt1 + 32 + srow) * D_MODEL + scol, &Ks[nxt][2048 + wave * 512]);
      load_lds16(vbase + (size_t)srow * SEQQ + kt1 + scol,           &Vs[nxt][wave * 512]);
      load_lds16(vbase + (size_t)(32 + srow) * SEQQ + kt1 + scol,    &Vs[nxt][2048 + wave * 512]);
    }
    const int kt = t * 64;
    const bool doA = (t <= p);   // block-uniform

    // ---- batched K fragment loads: 8 ds_read_b128 in flight, one wait ----
    short8 kf[4][2];
#pragma unroll
    for (int ni = 0; ni < 4; ++ni) {
      const int krow = (ni * 16 + l15) * 64;
      kf[ni][0] = *(const short8*)&Ks[cur][krow + ((quad * 8) ^ swz)];
      kf[ni][1] = *(const short8*)&Ks[cur][krow + ((32 + quad * 8) ^ swz)];
    }

    uint32_t wA[4][2], wB[4][2];
    // ---- QK^T + softmax (kf dies here; w arrays carry P to PV) ----
#pragma unroll
    for (int ni = 0; ni < 4; ++ni) {
      if (doA) {
        floatx4 s = (floatx4){0.f, 0.f, 0.f, 0.f};
        s = mfma16(kf[ni][0], qfA[0], s);
        s = mfma16(kf[ni][1], qfA[1], s);
        if (t == p) {   // diagonal tile of A: mask key > q
          const int qg = qwA + l15;
          const int kg = kt + ni * 16 + quad * 4;
#pragma unroll
          for (int r = 0; r < 4; ++r)
            if (kg + r > qg) s[r] = -1e30f;
        }
        softmax_ni(s, lAp, wA[ni]);
      }
      {
        floatx4 s = (floatx4){0.f, 0.f, 0.f, 0.f};
        s = mfma16(kf[ni][0], qfB[0], s);
        s = mfma16(kf[ni][1], qfB[1], s);
        if (t == nT - 1) {   // diagonal tile of B
          const int qg = qwB + l15;
          const int kg = kt + ni * 16 + quad * 4;
#pragma unroll
          for (int r = 0; r < 4; ++r)
            if (kg + r > qg) s[r] = -1e30f;
        }
        softmax_ni(s, lBp, wB[ni]);
      }
    }

    // ---- batched V fragment loads (kf dead; vf live only through PV) ----
    short8 vf[2][4];
#pragma unroll
    for (int kc = 0; kc < 2; ++kc)
#pragma unroll
      for (int di = 0; di < 4; ++di)
        vf[kc][di] = *(const short8*)&Vs[cur][(di * 16 + l15) * 64 +
                                             ((kc * 32 + quad * 8) ^ swz)];

    // ---- PV; pf via in-register quad-transpose, vf shared by A and B ----
#pragma unroll
    for (int kc = 0; kc < 2; ++kc) {
      const short8 pfB = pf_prep(wB, kc);
      if (doA) {
        const short8 pfA = pf_prep(wA, kc);
#pragma unroll
        for (int di = 0; di < 4; ++di)
          accA[di] = mfma16(pfA, vf[kc][di], accA[di]);
      }
#pragma unroll
      for (int di = 0; di < 4; ++di)
        accB[di] = mfma16(pfB, vf[kc][di], accB[di]);
    }
  }

  // l reduce: across the 4 quad groups (same l15) -> every lane holds l(q=l15)
  lAp += __shfl_xor(lAp, 16); lAp += __shfl_xor(lAp, 32);
  lBp += __shfl_xor(lBp, 16); lBp += __shfl_xor(lBp, 32);

  // epilogue: O rows q=quad*4+r, cols d=di*16+l15; l for row via shfl
  {
    u16* orow = O + (size_t)(b * SEQQ + qwA + quad * 4) * D_MODEL + h * HDIM + l15;
#pragma unroll
    for (int r = 0; r < 4; ++r) {
      const float inv = 1.0f / __shfl(lAp, quad * 4 + r, 16);
#pragma unroll
      for (int di = 0; di < 4; ++di)
        orow[(size_t)r * D_MODEL + di * 16] = f2bf(accA[di][r] * inv);
    }
  }
  {
    u16* orow = O + (size_t)(b * SEQQ + qwB + quad * 4) * D_MODEL + h * HDIM + l15;
#pragma unroll
    for (int r = 0; r < 4; ++r) {
      const float inv = 1.0f / __shfl(lBp, quad * 4 + r, 16);
#pragma unroll
      for (int di = 0; di < 4; ++di)
        orow[(size_t)r * D_MODEL + di * 16] = f2bf(accB[di][r] * inv);
    }
  }
}

// ---------------------------------------------------------------- launch
extern "C" void kernel_launch(void* const* d_in, const int* in_sizes, int n_in,
                              void* d_out, int out_size, void* d_ws, size_t ws_size,
                              hipStream_t stream) {
  const float* X  = (const float*)d_in[0];
  const float* Wq = (const float*)d_in[1];
  const float* Wk = (const float*)d_in[2];
  const float* Wv = (const float*)d_in[3];
  const float* Wo = (const float*)d_in[4];
  const float* bo = (const float*)d_in[5];
  float* out = (float*)d_out;

  u16* ws = (u16*)d_ws;
  const size_t NE = (size_t)MTOT * D_MODEL;    // 8,388,608
  u16* Xb  = ws;
  u16* Qb  = Xb + NE;
  u16* Kb  = Qb + NE;
  u16* Vt  = Kb + NE;          // V projection written directly transposed
  u16* Cb  = Vt + NE;
  u16* Wqb = Cb + NE;
  u16* Wkb = Wqb + (size_t)D_MODEL * D_MODEL;
  u16* Wvb = Wkb + (size_t)D_MODEL * D_MODEL;
  u16* Wob = Wvb + (size_t)D_MODEL * D_MODEL;

  const float SCL2E = 0.18033688f;   // (1/sqrt(64)) * log2(e), folded into Q

  // 1. all casts in one launch
  k_cast_all<<<12288, 256, 0, stream>>>(X, Wq, Wk, Wv, Wo, Xb, Wqb, Wkb, Wvb, Wob);

  // 2. fused QKV projections (Q pre-scaled; V written transposed into Vt)
  k_gemm_bt<<<dim3(D_MODEL / 128, MTOT / 128, 3), 256, 0, stream>>>(
      Xb, Wqb, Wkb, Wvb, Qb, Kb, Vt, nullptr, MTOT, D_MODEL, D_MODEL, 0, SCL2E);

  // 3. causal flash attention, paired 64-row q-tiles -> Cb [8192][1024]
  k_attn<<<dim3(16, NBATCH * NHEAD), 256, 0, stream>>>(Qb, Kb, Vt, Cb);

  // 4. output projection + bias, f32 out
  k_gemm_bt<<<dim3(D_MODEL / 128, MTOT / 128, 1), 256, 0, stream>>>(
      Cb, Wob, Wob, Wob, out, out, nullptr, bo, MTOT, D_MODEL, D_MODEL, 1, 1.0f);
}

// Round 5
// 273.104 us; speedup vs baseline: 1.4923x; 1.0773x over previous
//
#include <hip/hip_runtime.h>
#include <cstdint>
#include <cstddef>

// Problem constants (MultiHeadAttention: B=4, T=2048, d_model=1024, H=16, hd=64)
#define D_MODEL 1024
#define SEQQ    2048
#define NBATCH  4
#define NHEAD   16
#define HDIM    64
#define MTOT    (NBATCH * SEQQ)   // 8192 rows

typedef __attribute__((ext_vector_type(8))) short short8;   // 8 x bf16 (4 VGPRs) — MFMA A/B frag
typedef __attribute__((ext_vector_type(4))) float floatx4;  // MFMA C/D frag
typedef unsigned short u16;                                  // bf16 bits

__device__ __forceinline__ u16 f2bf(float f) {
  union { float f; uint32_t u; } a; a.f = f;
  uint32_t u = a.u;
  u += 0x7fffu + ((u >> 16) & 1u);   // RN-even
  return (u16)(u >> 16);
}

__device__ __forceinline__ floatx4 mfma16(short8 a, short8 b, floatx4 c) {
  return __builtin_amdgcn_mfma_f32_16x16x32_bf16(a, b, c, 0, 0, 0);
}

// async global->LDS, 16B per lane. LDS dest = wave-uniform base + lane*16.
__device__ __forceinline__ void load_lds16(const void* g, void* l) {
  __builtin_amdgcn_global_load_lds(
      (const __attribute__((address_space(1))) uint32_t*)g,
      (__attribute__((address_space(3))) uint32_t*)l, 16, 0, 0);
}

// ---------------------------------------------------------------- fused casts f32->bf16
// blocks [0, 8192): X. blocks [8192, 12288): weights, 1024 blocks each.
__global__ __launch_bounds__(256) void k_cast_all(
    const float* __restrict__ X, const float* __restrict__ w0,
    const float* __restrict__ w1, const float* __restrict__ w2,
    const float* __restrict__ w3,
    u16* __restrict__ xb, u16* __restrict__ y0, u16* __restrict__ y1,
    u16* __restrict__ y2, u16* __restrict__ y3) {
  const int bx = blockIdx.x;
  const float* src; u16* dst; int i;
  if (bx < 8192) {
    src = X; dst = xb; i = (bx * 256 + threadIdx.x) * 4;
  } else {
    const int w = (bx - 8192) >> 10;
    src = (w == 0) ? w0 : (w == 1) ? w1 : (w == 2) ? w2 : w3;
    dst = (w == 0) ? y0 : (w == 1) ? y1 : (w == 2) ? y2 : y3;
    i = (((bx - 8192) & 1023) * 256 + threadIdx.x) * 4;
  }
  float4 v = *(const float4*)(src + i);
  ushort4 o;
  o.x = f2bf(v.x); o.y = f2bf(v.y); o.z = f2bf(v.z); o.w = f2bf(v.w);
  *(ushort4*)(dst + i) = o;
}

// ---------------------------------------------------------------- GEMM  C = A @ B^T (+bias)
// ascaleQ: extra scale on the z==0 output (folds 1/sqrt(hd)*log2e into Q).
// z==2 (V projection): epilogue writes TRANSPOSED into Vt [bh][64][2048].
__global__ __launch_bounds__(256) void k_gemm_bt(
    const u16* __restrict__ A,
    const u16* __restrict__ B0, const u16* __restrict__ B1, const u16* __restrict__ B2,
    void* __restrict__ C0, void* __restrict__ C1, u16* __restrict__ VtOut,
    const float* __restrict__ bias, int M, int N, int K, int f32out, float ascaleQ) {
  __shared__ __align__(16) u16 As[128 * 64];
  __shared__ __align__(16) u16 Bs[128 * 64];
  const int tid = threadIdx.x;
  const int lane = tid & 63, wave = tid >> 6;
  const int quad = lane >> 4, l15 = lane & 15;
  const int m0 = blockIdx.y * 128, n0 = blockIdx.x * 128;
  const int wr = wave >> 1, wc = wave & 1;
  const u16* Bm = (blockIdx.z == 0) ? B0 : (blockIdx.z == 1 ? B1 : B2);
  void* Cm = (blockIdx.z == 0) ? C0 : C1;
  const float ascale = (blockIdx.z == 0) ? ascaleQ : 1.0f;

  floatx4 acc[4][4];
#pragma unroll
  for (int i = 0; i < 4; ++i)
#pragma unroll
    for (int j = 0; j < 4; ++j) acc[i][j] = (floatx4){0.f, 0.f, 0.f, 0.f};

  const int srow = tid >> 3;                       // 0..31
  const int scolx = ((tid & 7) * 8) ^ ((srow & 7) * 8);  // swizzled source column
  const u16* Ag = A + (size_t)(m0 + srow) * K + scolx;
  const u16* Bg = Bm + (size_t)(n0 + srow) * K + scolx;

  for (int kt = 0; kt < K; kt += 64) {
    __syncthreads();
#pragma unroll
    for (int p = 0; p < 4; ++p) {
      load_lds16(Ag + (size_t)(p * 32) * K + kt, &As[p * 2048 + wave * 512]);
      load_lds16(Bg + (size_t)(p * 32) * K + kt, &Bs[p * 2048 + wave * 512]);
    }
    __syncthreads();

    short8 af[2][4], bfg[2][4];
#pragma unroll
    for (int ks = 0; ks < 2; ++ks) {
      const int kkx = (ks * 32 + quad * 8) ^ ((l15 & 7) * 8);
#pragma unroll
      for (int i = 0; i < 4; ++i) {
        af[ks][i]  = *(const short8*)&As[(wr * 64 + i * 16 + l15) * 64 + kkx];
        bfg[ks][i] = *(const short8*)&Bs[(wc * 64 + i * 16 + l15) * 64 + kkx];
      }
    }
#pragma unroll
    for (int ks = 0; ks < 2; ++ks)
#pragma unroll
      for (int mi = 0; mi < 4; ++mi)
#pragma unroll
        for (int ni = 0; ni < 4; ++ni)
          acc[mi][ni] = mfma16(af[ks][mi], bfg[ks][ni], acc[mi][ni]);
  }

  // Epilogue. C/D layout: col = lane&15, row = quad*4 + reg (m89-verified).
  if (blockIdx.z == 2) {
    // transposed V write: Vt[(b*16+h)*64 + d][t], 4 regs = t..t+3 contiguous
#pragma unroll
    for (int mi = 0; mi < 4; ++mi) {
#pragma unroll
      for (int ni = 0; ni < 4; ++ni) {
        const int row = m0 + wr * 64 + mi * 16 + quad * 4;   // token
        const int col = n0 + wc * 64 + ni * 16 + l15;        // channel
        const int b = row >> 11, t = row & 2047;
        const int h = col >> 6, d = col & 63;
        ushort4 pk;
        pk.x = f2bf(acc[mi][ni][0]); pk.y = f2bf(acc[mi][ni][1]);
        pk.z = f2bf(acc[mi][ni][2]); pk.w = f2bf(acc[mi][ni][3]);
        *(ushort4*)(VtOut + (((size_t)(b * 16 + h) * 64 + d) * SEQQ + t)) = pk;
      }
    }
    return;
  }
#pragma unroll
  for (int mi = 0; mi < 4; ++mi) {
#pragma unroll
    for (int ni = 0; ni < 4; ++ni) {
      const int row = m0 + wr * 64 + mi * 16 + quad * 4;
      const int col = n0 + wc * 64 + ni * 16 + l15;
      const float bv = bias ? bias[col] : 0.f;
#pragma unroll
      for (int r = 0; r < 4; ++r) {
        const float v = acc[mi][ni][r] * ascale + bv;
        if (f32out) ((float*)Cm)[(size_t)(row + r) * N + col] = v;
        else        ((u16*)Cm)[(size_t)(row + r) * N + col] = f2bf(v);
      }
    }
  }
}

// ---------------------------------------------------------------- flash attention
// r0 structure restored (measured best 94.5us): paired q-tiles (p,31-p),
// 4 waves x 16 q, double-buffered K/V, ONE barrier/iter, Ps LDS bounce for the
// P redistribution (its latency hides under the B-tile QK^T MFMAs — measured
// faster than the permlane in-register transpose, which serializes ~16 VALU
// ops on the wave's own issue slot: r4 101us vs r0 94.5us).
// NEW THIS ROUND:
// 1. LOAD BALANCE: grid was (p=x, bh=y); linear%256 picks the CU under
//    round-robin dispatch, and 256%16==0 meant every CU's 4 blocks shared the
//    same p -> per-CU work spread 68..128 iters (2x tail). Remap (1D grid):
//    k=lin>>8, c=lin&255, a=c&7, p = (k&1)? 15-a : a, bh = ((c>>3)<<1)|(k>>1).
//    Stride-256 siblings now get p={a,15-a,a,15-a} -> 98 iters/CU, constant.
// 2. Ps bank conflicts: stride 72 -> 64 with per-row XOR-8 swizzle (same
//    scheme as K/V staging; write 8B / read 16B offsets XOR a 16B-granular
//    term, so alignment + write/read consistency hold). Kills the 3.24M
//    SQ_LDS_BANK_CONFLICT and shrinks LDS 51200 -> 49152.
__device__ __forceinline__ void softmax_pack(
    floatx4 (&st)[4], float& lp, u16* psw, int quad, int l15) {
#pragma unroll
  for (int ni = 0; ni < 4; ++ni) {
    const float p0 = __builtin_amdgcn_exp2f(st[ni][0]);
    const float p1 = __builtin_amdgcn_exp2f(st[ni][1]);
    const float p2 = __builtin_amdgcn_exp2f(st[ni][2]);
    const float p3 = __builtin_amdgcn_exp2f(st[ni][3]);
    lp += (p0 + p1) + (p2 + p3);
    uint2 pk;
    pk.x = __builtin_amdgcn_perm(__float_as_uint(p1), __float_as_uint(p0), 0x07060302u);
    pk.y = __builtin_amdgcn_perm(__float_as_uint(p3), __float_as_uint(p2), 0x07060302u);
    // row = q (l15), col = key, XOR-8 swizzled within the row
    *(uint2*)&psw[l15 * 64 + ((ni * 16 + quad * 4) ^ ((l15 & 7) * 8))] = pk;
  }
}

__device__ __forceinline__ void pv_mfma(
    floatx4 (&acc)[4], const u16* psw, const short8 (&vf)[2][4], int quad, int l15) {
#pragma unroll
  for (int kc = 0; kc < 2; ++kc) {
    const short8 pf = *(const short8*)&psw[l15 * 64 +
                                           ((kc * 32 + quad * 8) ^ ((l15 & 7) * 8))];
#pragma unroll
    for (int di = 0; di < 4; ++di)
      acc[di] = mfma16(pf, vf[kc][di], acc[di]);
  }
}

__global__ __launch_bounds__(256) void k_attn(
    const u16* __restrict__ Q, const u16* __restrict__ Kg,
    const u16* __restrict__ Vt, u16* __restrict__ O) {
  __shared__ __align__(16) u16 Ks[2][64 * 64];
  __shared__ __align__(16) u16 Vs[2][64 * 64];
  __shared__ __align__(16) u16 Ps[4][2][16 * 64];  // [wave][subtile A/B], swizzled
  const int tid = threadIdx.x, lane = tid & 63, wave = tid >> 6;
  const int quad = lane >> 4, l15 = lane & 15;

  // balanced (p, bh) derivation — see header comment
  const int lin = blockIdx.x;
  const int kgrp = lin >> 8, c = lin & 255;
  const int a = c & 7;
  const int p = (kgrp & 1) ? (15 - a) : a;          // pair index 0..15
  const int bh = ((c >> 3) << 1) | (kgrp >> 1);     // 0..63
  const int b = bh >> 4, h = bh & 15;

  const int qwA = 64 * p + wave * 16;
  const int qwB = SEQQ - 64 * (p + 1) + wave * 16;
  const int nT = 32 - p;                     // k-tiles for B (>= A's p+1)

  const u16* kbase = Kg + (size_t)(b * SEQQ) * D_MODEL + h * HDIM;
  const u16* vbase = Vt + (size_t)bh * (HDIM * SEQQ);

  const int srow = tid >> 3;                            // 0..31
  const int scol = ((tid & 7) * 8) ^ ((srow & 7) * 8);  // swizzled col 0..63

  // issue first staging before anything else
  {
    load_lds16(kbase + (size_t)srow * D_MODEL + scol,        &Ks[0][wave * 512]);
    load_lds16(kbase + (size_t)(32 + srow) * D_MODEL + scol, &Ks[0][2048 + wave * 512]);
    load_lds16(vbase + (size_t)srow * SEQQ + scol,           &Vs[0][wave * 512]);
    load_lds16(vbase + (size_t)(32 + srow) * SEQQ + scol,    &Vs[0][2048 + wave * 512]);
  }

  // Q fragments ([idx=l15][k=quad*8+j]); Q pre-scaled by 1/sqrt(hd)*log2e.
  short8 qfA[2], qfB[2];
  {
    const u16* qa = Q + (size_t)(b * SEQQ + qwA + l15) * D_MODEL + h * HDIM;
    const u16* qb = Q + (size_t)(b * SEQQ + qwB + l15) * D_MODEL + h * HDIM;
#pragma unroll
    for (int ks = 0; ks < 2; ++ks) {
      qfA[ks] = *(const short8*)(qa + ks * 32 + quad * 8);
      qfB[ks] = *(const short8*)(qb + ks * 32 + quad * 8);
    }
  }

  floatx4 accA[4], accB[4];
  float lAp = 0.f, lBp = 0.f;     // per-lane partial softmax denominators
#pragma unroll
  for (int i = 0; i < 4; ++i) {
    accA[i] = (floatx4){0.f, 0.f, 0.f, 0.f};
    accB[i] = (floatx4){0.f, 0.f, 0.f, 0.f};
  }

  u16* pswA = &Ps[wave][0][0];
  u16* pswB = &Ps[wave][1][0];

  for (int t = 0; t < nT; ++t) {
    const int cur = t & 1;
    __syncthreads();   // drains stage(t) (vmcnt) + all reads of buf[cur^1]
    if (t + 1 < nT) {  // prefetch next tile into the other buffer
      const int kt1 = (t + 1) * 64, nxt = cur ^ 1;
      load_lds16(kbase + (size_t)(kt1 + srow) * D_MODEL + scol,      &Ks[nxt][wave * 512]);
      load_lds16(kbase + (size_t)(kt1 + 32 + srow) * D_MODEL + scol, &Ks[nxt][2048 + wave * 512]);
      load_lds16(vbase + (size_t)srow * SEQQ + kt1 + scol,           &Vs[nxt][wave * 512]);
      load_lds16(vbase + (size_t)(32 + srow) * SEQQ + kt1 + scol,    &Vs[nxt][2048 + wave * 512]);
    }
    const int kt = t * 64;

    // K fragments ([key=l15][d=quad*8+j]), shared by both q-tiles
    short8 kf[4][2];
#pragma unroll
    for (int ni = 0; ni < 4; ++ni)
#pragma unroll
      for (int ks = 0; ks < 2; ++ks)
        kf[ni][ks] = *(const short8*)&Ks[cur][(ni * 16 + l15) * 64 +
                                            ((ks * 32 + quad * 8) ^ ((l15 & 7) * 8))];
    // V fragments ([d=l15][key=quad*8+j]), shared by both q-tiles
    short8 vf[2][4];
#pragma unroll
    for (int kc = 0; kc < 2; ++kc)
#pragma unroll
      for (int di = 0; di < 4; ++di)
        vf[kc][di] = *(const short8*)&Vs[cur][(di * 16 + l15) * 64 +
                                             ((kc * 32 + quad * 8) ^ ((l15 & 7) * 8))];

    const bool doA = (t <= p);   // block-uniform
    if (doA) {
      floatx4 st[4];   // S^T: row=key (quad*4+r, tile ni), col=q (l15)
#pragma unroll
      for (int ni = 0; ni < 4; ++ni) {
        floatx4 s = (floatx4){0.f, 0.f, 0.f, 0.f};
        s = mfma16(kf[ni][0], qfA[0], s);
        s = mfma16(kf[ni][1], qfA[1], s);
        st[ni] = s;
      }
      if (t == p) {   // diagonal tile of A: mask key > q
        const int qg = qwA + l15;
#pragma unroll
        for (int ni = 0; ni < 4; ++ni) {
          const int kg = kt + ni * 16 + quad * 4;
#pragma unroll
          for (int r = 0; r < 4; ++r)
            if (kg + r > qg) st[ni][r] = -1e30f;
        }
      }
      softmax_pack(st, lAp, pswA, quad, l15);
    }
    {
      floatx4 st[4];
#pragma unroll
      for (int ni = 0; ni < 4; ++ni) {
        floatx4 s = (floatx4){0.f, 0.f, 0.f, 0.f};
        s = mfma16(kf[ni][0], qfB[0], s);   // fills pswA write latency
        s = mfma16(kf[ni][1], qfB[1], s);
        st[ni] = s;
      }
      if (t == nT - 1) {   // diagonal tile of B
        const int qg = qwB + l15;
#pragma unroll
        for (int ni = 0; ni < 4; ++ni) {
          const int kg = kt + ni * 16 + quad * 4;
#pragma unroll
          for (int r = 0; r < 4; ++r)
            if (kg + r > qg) st[ni][r] = -1e30f;
        }
      }
      softmax_pack(st, lBp, pswB, quad, l15);
    }
    asm volatile("s_waitcnt lgkmcnt(0)" ::: "memory");  // single wait per iter
    if (doA) pv_mfma(accA, pswA, vf, quad, l15);
    pv_mfma(accB, pswB, vf, quad, l15);
  }

  // l reduce: across the 4 quad groups (same l15) -> every lane holds l(q=l15)
  lAp += __shfl_xor(lAp, 16); lAp += __shfl_xor(lAp, 32);
  lBp += __shfl_xor(lBp, 16); lBp += __shfl_xor(lBp, 32);

  // epilogue: O rows q=quad*4+r, cols d=di*16+l15; l for row via shfl
  {
    u16* orow = O + (size_t)(b * SEQQ + qwA + quad * 4) * D_MODEL + h * HDIM + l15;
#pragma unroll
    for (int r = 0; r < 4; ++r) {
      const float inv = 1.0f / __shfl(lAp, quad * 4 + r, 16);
#pragma unroll
      for (int di = 0; di < 4; ++di)
        orow[(size_t)r * D_MODEL + di * 16] = f2bf(accA[di][r] * inv);
    }
  }
  {
    u16* orow = O + (size_t)(b * SEQQ + qwB + quad * 4) * D_MODEL + h * HDIM + l15;
#pragma unroll
    for (int r = 0; r < 4; ++r) {
      const float inv = 1.0f / __shfl(lBp, quad * 4 + r, 16);
#pragma unroll
      for (int di = 0; di < 4; ++di)
        orow[(size_t)r * D_MODEL + di * 16] = f2bf(accB[di][r] * inv);
    }
  }
}

// ---------------------------------------------------------------- launch
extern "C" void kernel_launch(void* const* d_in, const int* in_sizes, int n_in,
                              void* d_out, int out_size, void* d_ws, size_t ws_size,
                              hipStream_t stream) {
  const float* X  = (const float*)d_in[0];
  const float* Wq = (const float*)d_in[1];
  const float* Wk = (const float*)d_in[2];
  const float* Wv = (const float*)d_in[3];
  const float* Wo = (const float*)d_in[4];
  const float* bo = (const float*)d_in[5];
  float* out = (float*)d_out;

  u16* ws = (u16*)d_ws;
  const size_t NE = (size_t)MTOT * D_MODEL;    // 8,388,608
  u16* Xb  = ws;
  u16* Qb  = Xb + NE;
  u16* Kb  = Qb + NE;
  u16* Vt  = Kb + NE;          // V projection written directly transposed
  u16* Cb  = Vt + NE;
  u16* Wqb = Cb + NE;
  u16* Wkb = Wqb + (size_t)D_MODEL * D_MODEL;
  u16* Wvb = Wkb + (size_t)D_MODEL * D_MODEL;
  u16* Wob = Wvb + (size_t)D_MODEL * D_MODEL;

  const float SCL2E = 0.18033688f;   // (1/sqrt(64)) * log2(e), folded into Q

  // 1. all casts in one launch
  k_cast_all<<<12288, 256, 0, stream>>>(X, Wq, Wk, Wv, Wo, Xb, Wqb, Wkb, Wvb, Wob);

  // 2. fused QKV projections (Q pre-scaled; V written transposed into Vt)
  k_gemm_bt<<<dim3(D_MODEL / 128, MTOT / 128, 3), 256, 0, stream>>>(
      Xb, Wqb, Wkb, Wvb, Qb, Kb, Vt, nullptr, MTOT, D_MODEL, D_MODEL, 0, SCL2E);

  // 3. causal flash attention, balanced 1D grid -> Cb [8192][1024]
  k_attn<<<1024, 256, 0, stream>>>(Qb, Kb, Vt, Cb);

  // 4. output projection + bias, f32 out
  k_gemm_bt<<<dim3(D_MODEL / 128, MTOT / 128, 1), 256, 0, stream>>>(
      Cb, Wob, Wob, Wob, out, out, nullptr, bo, MTOT, D_MODEL, D_MODEL, 1, 1.0f);
}

// Round 6
// 267.636 us; speedup vs baseline: 1.5227x; 1.0204x over previous
//
#include <hip/hip_runtime.h>
#include <cstdint>
#include <cstddef>

// Problem constants (MultiHeadAttention: B=4, T=2048, d_model=1024, H=16, hd=64)
#define D_MODEL 1024
#define SEQQ    2048
#define NBATCH  4
#define NHEAD   16
#define HDIM    64
#define MTOT    (NBATCH * SEQQ)   // 8192 rows

typedef __attribute__((ext_vector_type(8))) short short8;   // 8 x bf16 (4 VGPRs) — MFMA A/B frag
typedef __attribute__((ext_vector_type(4))) float floatx4;  // MFMA C/D frag
typedef unsigned short u16;                                  // bf16 bits

__device__ __forceinline__ u16 f2bf(float f) {
  union { float f; uint32_t u; } a; a.f = f;
  uint32_t u = a.u;
  u += 0x7fffu + ((u >> 16) & 1u);   // RN-even
  return (u16)(u >> 16);
}

__device__ __forceinline__ floatx4 mfma16(short8 a, short8 b, floatx4 c) {
  return __builtin_amdgcn_mfma_f32_16x16x32_bf16(a, b, c, 0, 0, 0);
}

// async global->LDS, 16B per lane. LDS dest = wave-uniform base + lane*16.
__device__ __forceinline__ void load_lds16(const void* g, void* l) {
  __builtin_amdgcn_global_load_lds(
      (const __attribute__((address_space(1))) uint32_t*)g,
      (__attribute__((address_space(3))) uint32_t*)l, 16, 0, 0);
}

// ---------------------------------------------------------------- fused casts f32->bf16
// blocks [0, 8192): X. blocks [8192, 12288): weights, 1024 blocks each.
__global__ __launch_bounds__(256) void k_cast_all(
    const float* __restrict__ X, const float* __restrict__ w0,
    const float* __restrict__ w1, const float* __restrict__ w2,
    const float* __restrict__ w3,
    u16* __restrict__ xb, u16* __restrict__ y0, u16* __restrict__ y1,
    u16* __restrict__ y2, u16* __restrict__ y3) {
  const int bx = blockIdx.x;
  const float* src; u16* dst; int i;
  if (bx < 8192) {
    src = X; dst = xb; i = (bx * 256 + threadIdx.x) * 4;
  } else {
    const int w = (bx - 8192) >> 10;
    src = (w == 0) ? w0 : (w == 1) ? w1 : (w == 2) ? w2 : w3;
    dst = (w == 0) ? y0 : (w == 1) ? y1 : (w == 2) ? y2 : y3;
    i = (((bx - 8192) & 1023) * 256 + threadIdx.x) * 4;
  }
  float4 v = *(const float4*)(src + i);
  ushort4 o;
  o.x = f2bf(v.x); o.y = f2bf(v.y); o.z = f2bf(v.z); o.w = f2bf(v.w);
  *(ushort4*)(dst + i) = o;
}

// ---------------------------------------------------------------- GEMM  C = A @ B^T (+bias)
// ascaleQ: extra scale on the z==0 output (folds 1/sqrt(hd)*log2e into Q).
// z==2 (V projection): epilogue writes TRANSPOSED into Vt [bh][64][2048].
__global__ __launch_bounds__(256) void k_gemm_bt(
    const u16* __restrict__ A,
    const u16* __restrict__ B0, const u16* __restrict__ B1, const u16* __restrict__ B2,
    void* __restrict__ C0, void* __restrict__ C1, u16* __restrict__ VtOut,
    const float* __restrict__ bias, int M, int N, int K, int f32out, float ascaleQ) {
  __shared__ __align__(16) u16 As[128 * 64];
  __shared__ __align__(16) u16 Bs[128 * 64];
  const int tid = threadIdx.x;
  const int lane = tid & 63, wave = tid >> 6;
  const int quad = lane >> 4, l15 = lane & 15;
  const int m0 = blockIdx.y * 128, n0 = blockIdx.x * 128;
  const int wr = wave >> 1, wc = wave & 1;
  const u16* Bm = (blockIdx.z == 0) ? B0 : (blockIdx.z == 1 ? B1 : B2);
  void* Cm = (blockIdx.z == 0) ? C0 : C1;
  const float ascale = (blockIdx.z == 0) ? ascaleQ : 1.0f;

  floatx4 acc[4][4];
#pragma unroll
  for (int i = 0; i < 4; ++i)
#pragma unroll
    for (int j = 0; j < 4; ++j) acc[i][j] = (floatx4){0.f, 0.f, 0.f, 0.f};

  const int srow = tid >> 3;                       // 0..31
  const int scolx = ((tid & 7) * 8) ^ ((srow & 7) * 8);  // swizzled source column
  const u16* Ag = A + (size_t)(m0 + srow) * K + scolx;
  const u16* Bg = Bm + (size_t)(n0 + srow) * K + scolx;

  for (int kt = 0; kt < K; kt += 64) {
    __syncthreads();
#pragma unroll
    for (int p = 0; p < 4; ++p) {
      load_lds16(Ag + (size_t)(p * 32) * K + kt, &As[p * 2048 + wave * 512]);
      load_lds16(Bg + (size_t)(p * 32) * K + kt, &Bs[p * 2048 + wave * 512]);
    }
    __syncthreads();

    short8 af[2][4], bfg[2][4];
#pragma unroll
    for (int ks = 0; ks < 2; ++ks) {
      const int kkx = (ks * 32 + quad * 8) ^ ((l15 & 7) * 8);
#pragma unroll
      for (int i = 0; i < 4; ++i) {
        af[ks][i]  = *(const short8*)&As[(wr * 64 + i * 16 + l15) * 64 + kkx];
        bfg[ks][i] = *(const short8*)&Bs[(wc * 64 + i * 16 + l15) * 64 + kkx];
      }
    }
#pragma unroll
    for (int ks = 0; ks < 2; ++ks)
#pragma unroll
      for (int mi = 0; mi < 4; ++mi)
#pragma unroll
        for (int ni = 0; ni < 4; ++ni)
          acc[mi][ni] = mfma16(af[ks][mi], bfg[ks][ni], acc[mi][ni]);
  }

  // Epilogue. C/D layout: col = lane&15, row = quad*4 + reg (m89-verified).
  if (blockIdx.z == 2) {
    // transposed V write: Vt[(b*16+h)*64 + d][t], 4 regs = t..t+3 contiguous
#pragma unroll
    for (int mi = 0; mi < 4; ++mi) {
#pragma unroll
      for (int ni = 0; ni < 4; ++ni) {
        const int row = m0 + wr * 64 + mi * 16 + quad * 4;   // token
        const int col = n0 + wc * 64 + ni * 16 + l15;        // channel
        const int b = row >> 11, t = row & 2047;
        const int h = col >> 6, d = col & 63;
        ushort4 pk;
        pk.x = f2bf(acc[mi][ni][0]); pk.y = f2bf(acc[mi][ni][1]);
        pk.z = f2bf(acc[mi][ni][2]); pk.w = f2bf(acc[mi][ni][3]);
        *(ushort4*)(VtOut + (((size_t)(b * 16 + h) * 64 + d) * SEQQ + t)) = pk;
      }
    }
    return;
  }
#pragma unroll
  for (int mi = 0; mi < 4; ++mi) {
#pragma unroll
    for (int ni = 0; ni < 4; ++ni) {
      const int row = m0 + wr * 64 + mi * 16 + quad * 4;
      const int col = n0 + wc * 64 + ni * 16 + l15;
      const float bv = bias ? bias[col] : 0.f;
#pragma unroll
      for (int r = 0; r < 4; ++r) {
        const float v = acc[mi][ni][r] * ascale + bv;
        if (f32out) ((float*)Cm)[(size_t)(row + r) * N + col] = v;
        else        ((u16*)Cm)[(size_t)(row + r) * N + col] = f2bf(v);
      }
    }
  }
}

// ---------------------------------------------------------------- flash attention
// ROUND-6: 8-wave blocks (512 threads) — TWO q-tile pairs per block sharing one
// K/V staging stream. Waves 0-3 own pair a=2g, waves 4-7 own pair a=2g+1
// (adjacent k-ranges differ by 1 iter -> ~1 idle iter/block). Block-iterations
// drop 25088 -> 12800 (-49%); per-iter staging/barrier cost amortized over 2x
// compute. LDS: Ks 16K + Vs 16K + Ps 32K = 64 KiB -> 2 blocks/CU = 4 waves/SIMD
// (up from 3). Grid 512 = exactly 2 resident/CU; the balance remap pairs g with
// 7-g on each CU -> 50 iters/CU constant.
// Retained from r5 (measured): Ps LDS bounce (beats permlane: r4 101 vs 94.5),
// XOR-swizzled Ps stride 64, one barrier/iter, double-buffered K/V.
__device__ __forceinline__ void softmax_pack(
    floatx4 (&st)[4], float& lp, u16* psw, int quad, int l15) {
#pragma unroll
  for (int ni = 0; ni < 4; ++ni) {
    const float p0 = __builtin_amdgcn_exp2f(st[ni][0]);
    const float p1 = __builtin_amdgcn_exp2f(st[ni][1]);
    const float p2 = __builtin_amdgcn_exp2f(st[ni][2]);
    const float p3 = __builtin_amdgcn_exp2f(st[ni][3]);
    lp += (p0 + p1) + (p2 + p3);
    uint2 pk;
    pk.x = __builtin_amdgcn_perm(__float_as_uint(p1), __float_as_uint(p0), 0x07060302u);
    pk.y = __builtin_amdgcn_perm(__float_as_uint(p3), __float_as_uint(p2), 0x07060302u);
    // row = q (l15), col = key, XOR-8 swizzled within the row
    *(uint2*)&psw[l15 * 64 + ((ni * 16 + quad * 4) ^ ((l15 & 7) * 8))] = pk;
  }
}

__device__ __forceinline__ void pv_mfma(
    floatx4 (&acc)[4], const u16* psw, const short8 (&vf)[2][4], int quad, int l15) {
#pragma unroll
  for (int kc = 0; kc < 2; ++kc) {
    const short8 pf = *(const short8*)&psw[l15 * 64 +
                                           ((kc * 32 + quad * 8) ^ ((l15 & 7) * 8))];
#pragma unroll
    for (int di = 0; di < 4; ++di)
      acc[di] = mfma16(pf, vf[kc][di], acc[di]);
  }
}

__global__ __launch_bounds__(512) void k_attn(
    const u16* __restrict__ Q, const u16* __restrict__ Kg,
    const u16* __restrict__ Vt, u16* __restrict__ O) {
  __shared__ __align__(16) u16 Ks[2][64 * 64];
  __shared__ __align__(16) u16 Vs[2][64 * 64];
  __shared__ __align__(16) u16 Ps[8][2][16 * 64];  // [wave][subtile A/B], swizzled
  const int tid = threadIdx.x, lane = tid & 63, wave = tid >> 6;
  const int quad = lane >> 4, l15 = lane & 15;

  // balanced (g, bh) derivation: CU c hosts blocks c and c+256 -> g and 7-g
  // -> per-CU loop total (32-2g)+(18+2g) = 50, constant.
  const int lin = blockIdx.x;
  const int c = lin & 255, k2 = lin >> 8;
  const int g = k2 ? (7 - (c & 7)) : (c & 7);       // pair-group 0..7
  const int bh = (c >> 3) | (k2 << 5);              // 0..63
  const int b = bh >> 4, h = bh & 15;

  const int wgrp = wave >> 2, wsub = wave & 3;
  const int a = 2 * g + wgrp;                // this wave's pair index 0..15
  const int qwA = 64 * a + wsub * 16;
  const int qwB = SEQQ - 64 * (a + 1) + wsub * 16;
  const int nT = 32 - 2 * g;                 // block loop count (= wgrp0's range)
  const int lastB = 31 - a;                  // B diag iteration (own range-1)

  const u16* kbase = Kg + (size_t)(b * SEQQ) * D_MODEL + h * HDIM;
  const u16* vbase = Vt + (size_t)bh * (HDIM * SEQQ);

  const int srow = tid >> 3;                            // 0..63 (512 threads)
  const int scol = ((tid & 7) * 8) ^ ((srow & 7) * 8);  // swizzled col 0..63

  // issue first staging before anything else: each wave stages 8 rows of K, V
  {
    load_lds16(kbase + (size_t)srow * D_MODEL + scol, &Ks[0][wave * 512]);
    load_lds16(vbase + (size_t)srow * SEQQ + scol,    &Vs[0][wave * 512]);
  }

  // Q fragments ([idx=l15][k=quad*8+j]); Q pre-scaled by 1/sqrt(hd)*log2e.
  short8 qfA[2], qfB[2];
  {
    const u16* qa = Q + (size_t)(b * SEQQ + qwA + l15) * D_MODEL + h * HDIM;
    const u16* qb = Q + (size_t)(b * SEQQ + qwB + l15) * D_MODEL + h * HDIM;
#pragma unroll
    for (int ks = 0; ks < 2; ++ks) {
      qfA[ks] = *(const short8*)(qa + ks * 32 + quad * 8);
      qfB[ks] = *(const short8*)(qb + ks * 32 + quad * 8);
    }
  }

  floatx4 accA[4], accB[4];
  float lAp = 0.f, lBp = 0.f;     // per-lane partial softmax denominators
#pragma unroll
  for (int i = 0; i < 4; ++i) {
    accA[i] = (floatx4){0.f, 0.f, 0.f, 0.f};
    accB[i] = (floatx4){0.f, 0.f, 0.f, 0.f};
  }

  u16* pswA = &Ps[wave][0][0];
  u16* pswB = &Ps[wave][1][0];

  for (int t = 0; t < nT; ++t) {
    const int cur = t & 1;
    __syncthreads();   // drains stage(t) (vmcnt) + all reads of buf[cur^1]
    if (t + 1 < nT) {  // prefetch next tile into the other buffer
      const int kt1 = (t + 1) * 64, nxt = cur ^ 1;
      load_lds16(kbase + (size_t)(kt1 + srow) * D_MODEL + scol, &Ks[nxt][wave * 512]);
      load_lds16(vbase + (size_t)srow * SEQQ + kt1 + scol,      &Vs[nxt][wave * 512]);
    }
    const int kt = t * 64;

    // K fragments ([key=l15][d=quad*8+j]), shared by both q-tiles of this wave
    short8 kf[4][2];
#pragma unroll
    for (int ni = 0; ni < 4; ++ni)
#pragma unroll
      for (int ks = 0; ks < 2; ++ks)
        kf[ni][ks] = *(const short8*)&Ks[cur][(ni * 16 + l15) * 64 +
                                            ((ks * 32 + quad * 8) ^ ((l15 & 7) * 8))];
    // V fragments ([d=l15][key=quad*8+j])
    short8 vf[2][4];
#pragma unroll
    for (int kc = 0; kc < 2; ++kc)
#pragma unroll
      for (int di = 0; di < 4; ++di)
        vf[kc][di] = *(const short8*)&Vs[cur][(di * 16 + l15) * 64 +
                                             ((kc * 32 + quad * 8) ^ ((l15 & 7) * 8))];

    const bool doA = (t <= a);       // wave-uniform
    const bool doB = (t <= lastB);   // wave-uniform (false only on wgrp1's last iter)
    if (doA) {
      floatx4 st[4];   // S^T: row=key (quad*4+r, tile ni), col=q (l15)
#pragma unroll
      for (int ni = 0; ni < 4; ++ni) {
        floatx4 s = (floatx4){0.f, 0.f, 0.f, 0.f};
        s = mfma16(kf[ni][0], qfA[0], s);
        s = mfma16(kf[ni][1], qfA[1], s);
        st[ni] = s;
      }
      if (t == a) {   // diagonal tile of A: mask key > q
        const int qg = qwA + l15;
#pragma unroll
        for (int ni = 0; ni < 4; ++ni) {
          const int kg = kt + ni * 16 + quad * 4;
#pragma unroll
          for (int r = 0; r < 4; ++r)
            if (kg + r > qg) st[ni][r] = -1e30f;
        }
      }
      softmax_pack(st, lAp, pswA, quad, l15);
    }
    if (doB) {
      floatx4 st[4];
#pragma unroll
      for (int ni = 0; ni < 4; ++ni) {
        floatx4 s = (floatx4){0.f, 0.f, 0.f, 0.f};
        s = mfma16(kf[ni][0], qfB[0], s);   // fills pswA write latency
        s = mfma16(kf[ni][1], qfB[1], s);
        st[ni] = s;
      }
      if (t == lastB) {   // diagonal tile of B
        const int qg = qwB + l15;
#pragma unroll
        for (int ni = 0; ni < 4; ++ni) {
          const int kg = kt + ni * 16 + quad * 4;
#pragma unroll
          for (int r = 0; r < 4; ++r)
            if (kg + r > qg) st[ni][r] = -1e30f;
        }
      }
      softmax_pack(st, lBp, pswB, quad, l15);
    }
    asm volatile("s_waitcnt lgkmcnt(0)" ::: "memory");  // single wait per iter
    if (doA) pv_mfma(accA, pswA, vf, quad, l15);
    if (doB) pv_mfma(accB, pswB, vf, quad, l15);
  }

  // l reduce: across the 4 quad groups (same l15) -> every lane holds l(q=l15)
  lAp += __shfl_xor(lAp, 16); lAp += __shfl_xor(lAp, 32);
  lBp += __shfl_xor(lBp, 16); lBp += __shfl_xor(lBp, 32);

  // epilogue: O rows q=quad*4+r, cols d=di*16+l15; l for row via shfl
  {
    u16* orow = O + (size_t)(b * SEQQ + qwA + quad * 4) * D_MODEL + h * HDIM + l15;
#pragma unroll
    for (int r = 0; r < 4; ++r) {
      const float inv = 1.0f / __shfl(lAp, quad * 4 + r, 16);
#pragma unroll
      for (int di = 0; di < 4; ++di)
        orow[(size_t)r * D_MODEL + di * 16] = f2bf(accA[di][r] * inv);
    }
  }
  {
    u16* orow = O + (size_t)(b * SEQQ + qwB + quad * 4) * D_MODEL + h * HDIM + l15;
#pragma unroll
    for (int r = 0; r < 4; ++r) {
      const float inv = 1.0f / __shfl(lBp, quad * 4 + r, 16);
#pragma unroll
      for (int di = 0; di < 4; ++di)
        orow[(size_t)r * D_MODEL + di * 16] = f2bf(accB[di][r] * inv);
    }
  }
}

// ---------------------------------------------------------------- launch
extern "C" void kernel_launch(void* const* d_in, const int* in_sizes, int n_in,
                              void* d_out, int out_size, void* d_ws, size_t ws_size,
                              hipStream_t stream) {
  const float* X  = (const float*)d_in[0];
  const float* Wq = (const float*)d_in[1];
  const float* Wk = (const float*)d_in[2];
  const float* Wv = (const float*)d_in[3];
  const float* Wo = (const float*)d_in[4];
  const float* bo = (const float*)d_in[5];
  float* out = (float*)d_out;

  u16* ws = (u16*)d_ws;
  const size_t NE = (size_t)MTOT * D_MODEL;    // 8,388,608
  u16* Xb  = ws;
  u16* Qb  = Xb + NE;
  u16* Kb  = Qb + NE;
  u16* Vt  = Kb + NE;          // V projection written directly transposed
  u16* Cb  = Vt + NE;
  u16* Wqb = Cb + NE;
  u16* Wkb = Wqb + (size_t)D_MODEL * D_MODEL;
  u16* Wvb = Wkb + (size_t)D_MODEL * D_MODEL;
  u16* Wob = Wvb + (size_t)D_MODEL * D_MODEL;

  const float SCL2E = 0.18033688f;   // (1/sqrt(64)) * log2(e), folded into Q

  // 1. all casts in one launch
  k_cast_all<<<12288, 256, 0, stream>>>(X, Wq, Wk, Wv, Wo, Xb, Wqb, Wkb, Wvb, Wob);

  // 2. fused QKV projections (Q pre-scaled; V written transposed into Vt)
  k_gemm_bt<<<dim3(D_MODEL / 128, MTOT / 128, 3), 256, 0, stream>>>(
      Xb, Wqb, Wkb, Wvb, Qb, Kb, Vt, nullptr, MTOT, D_MODEL, D_MODEL, 0, SCL2E);

  // 3. causal flash attention, 8-wave blocks, balanced 1D grid -> Cb [8192][1024]
  k_attn<<<512, 512, 0, stream>>>(Qb, Kb, Vt, Cb);

  // 4. output projection + bias, f32 out
  k_gemm_bt<<<dim3(D_MODEL / 128, MTOT / 128, 1), 256, 0, stream>>>(
      Cb, Wob, Wob, Wob, out, out, nullptr, bo, MTOT, D_MODEL, D_MODEL, 1, 1.0f);
}